// Round 7
// baseline (478.792 us; speedup 1.0000x reference)
//
#include <hip/hip_runtime.h>
#include <stdint.h>

typedef unsigned int u32;
#define TS 4096     // scan tile size (256 thr x 16)
#define KB 1024     // scatter buckets per side
#define LCNT 128    // max ids per bucket (ceil(N/KB) must be < LCNT)

// ---------- bf16 helpers ----------
__device__ __forceinline__ float bflo(u32 u) { return __uint_as_float(u << 16); }
__device__ __forceinline__ float bfhi(u32 u) { return __uint_as_float(u & 0xffff0000u); }
__device__ __forceinline__ u32 f2bf(float x) {
    u32 u = __float_as_uint(x);
    return (u + 0x7fffu + ((u >> 16) & 1u)) >> 16;   // RNE
}
__device__ __forceinline__ u32 pack2(float a, float b) { return f2bf(a) | (f2bf(b) << 16); }

__device__ __forceinline__ int bucket_of(int id, int total) {
    return (int)(((unsigned long long)id * KB) / (u32)total);
}
__device__ __forceinline__ int bstart(int b, int total) {
    return (int)(((unsigned long long)b * (u32)total + KB - 1) / KB);
}

// ---------- fused histogram + x->bf16 conversion ----------
__global__ void k_hist_cvt(const float2* __restrict__ x0, u32* __restrict__ xbf, int npairs,
                           const int* __restrict__ ni, const int* __restrict__ ei,
                           const int* __restrict__ nc_c, const int* __restrict__ ec_c,
                           int* __restrict__ deg_e, int* __restrict__ deg_n,
                           int* __restrict__ cnt_cn, int* __restrict__ cnt_ce,
                           int nnz, int n, int e) {
    int j = blockIdx.x * blockDim.x + threadIdx.x;
    if (j < npairs) { float2 v = x0[j]; xbf[j] = pack2(v.x, v.y); }
    if (j < nnz) {
        atomicAdd(&deg_e[ei[j]], 1);
        atomicAdd(&deg_n[ni[j]], 1);
    }
    if (j < n) atomicAdd(&cnt_cn[nc_c[j]], 1);
    if (j < e) atomicAdd(&cnt_ce[ec_c[j]], 1);
}

// ---------- 3-phase parallel exclusive scan over 4 arrays ----------
__device__ __forceinline__ void scan_sel(int b, int t0, int t01, int t012,
        const int* c0, int* o0, int* u0, int n0,
        const int* c1, int* o1, int* u1, int n1,
        const int* c2, int* o2, int* u2, int n2,
        const int* c3, int* o3, int* u3, int n3,
        const int*& cnt, int*& off, int*& cur, int& n, int& tile) {
    if (b < t0)        { cnt = c0; off = o0; cur = u0; n = n0; tile = b; }
    else if (b < t01)  { cnt = c1; off = o1; cur = u1; n = n1; tile = b - t0; }
    else if (b < t012) { cnt = c2; off = o2; cur = u2; n = n2; tile = b - t01; }
    else               { cnt = c3; off = o3; cur = u3; n = n3; tile = b - t012; }
}

__global__ void k_scan_p1(const int* c0, int n0, const int* c1, int n1,
                          const int* c2, int n2, const int* c3, int n3,
                          int t0, int t01, int t012, int* __restrict__ tilesum) {
    __shared__ int ws[4];
    int b = blockIdx.x;
    const int* cnt; int* off; int* cur; int n; int tile;
    scan_sel(b, t0, t01, t012, c0, nullptr, nullptr, n0, c1, nullptr, nullptr, n1,
             c2, nullptr, nullptr, n2, c3, nullptr, nullptr, n3, cnt, off, cur, n, tile);
    int base = tile * TS + threadIdx.x * 16;
    int s = 0;
#pragma unroll
    for (int i = 0; i < 16; ++i) { int idx = base + i; if (idx < n) s += cnt[idx]; }
    for (int d = 32; d; d >>= 1) s += __shfl_xor(s, d, 64);
    int lane = threadIdx.x & 63, w = threadIdx.x >> 6;
    if (lane == 0) ws[w] = s;
    __syncthreads();
    if (threadIdx.x == 0) tilesum[b] = ws[0] + ws[1] + ws[2] + ws[3];
}

__global__ void k_scan_p2(const int* __restrict__ tilesum, int* __restrict__ tilebase,
                          int t0, int t01, int t012, int t0123,
                          int* o0, int n0, int* o1, int n1, int* o2, int n2, int* o3, int n3) {
    if (threadIdx.x != 0 || blockIdx.x != 0) return;
    int carry = 0;
    for (int b = 0;    b < t0;    ++b) { tilebase[b] = carry; carry += tilesum[b]; } o0[n0] = carry;
    carry = 0;
    for (int b = t0;   b < t01;   ++b) { tilebase[b] = carry; carry += tilesum[b]; } o1[n1] = carry;
    carry = 0;
    for (int b = t01;  b < t012;  ++b) { tilebase[b] = carry; carry += tilesum[b]; } o2[n2] = carry;
    carry = 0;
    for (int b = t012; b < t0123; ++b) { tilebase[b] = carry; carry += tilesum[b]; } o3[n3] = carry;
}

__global__ void k_scan_p3(const int* c0, int* o0, int* u0, int n0,
                          const int* c1, int* o1, int* u1, int n1,
                          const int* c2, int* o2, int* u2, int n2,
                          const int* c3, int* o3, int* u3, int n3,
                          int t0, int t01, int t012, const int* __restrict__ tilebase) {
    __shared__ int wsum[4];
    int b = blockIdx.x;
    const int* cnt; int* off; int* cur; int n; int tile;
    scan_sel(b, t0, t01, t012, c0, o0, u0, n0, c1, o1, u1, n1,
             c2, o2, u2, n2, c3, o3, u3, n3, cnt, off, cur, n, tile);
    int lane = threadIdx.x & 63, w = threadIdx.x >> 6;
    int base = tile * TS + threadIdx.x * 16;
    int vals[16];
    int s = 0;
#pragma unroll
    for (int i = 0; i < 16; ++i) { int idx = base + i; int v = (idx < n) ? cnt[idx] : 0; vals[i] = v; s += v; }
    int inc = s;
    for (int d = 1; d < 64; d <<= 1) { int u = __shfl_up(inc, d, 64); if (lane >= d) inc += u; }
    if (lane == 63) wsum[w] = inc;
    __syncthreads();
    if (threadIdx.x == 0) {
        int acc = tilebase[b];
        for (int i = 0; i < 4; ++i) { int t = wsum[i]; wsum[i] = acc; acc += t; }
    }
    __syncthreads();
    int ex = wsum[w] + (inc - s);
#pragma unroll
    for (int i = 0; i < 16; ++i) {
        int idx = base + i;
        if (idx < n) { off[idx] = ex; cur[idx] = ex; }
        ex += vals[i];
    }
}

// ---------- binned scatter: bucket append counters init ----------
__global__ void k_binit(const int* __restrict__ off_e, const int* __restrict__ off_n,
                        int* __restrict__ bcur_e, int* __restrict__ bcur_n, int e, int n) {
    int t = blockIdx.x * blockDim.x + threadIdx.x;
    if (t < KB) bcur_e[t] = off_e[bstart(t, e)];
    else if (t < 2 * KB) { int b = t - KB; bcur_n[b] = off_n[bstart(b, n)]; }
}

// ---------- phase A: bucket-append packed pairs + component scatter ----------
__global__ void k_scat_a(const int* __restrict__ ni, const int* __restrict__ ei,
                         const int* __restrict__ nc_n, const int* __restrict__ nc_c,
                         const int* __restrict__ ec_e, const int* __restrict__ ec_c,
                         int* __restrict__ bcur_e, int* __restrict__ bcur_n,
                         u32* __restrict__ stg_e, u32* __restrict__ stg_n,
                         int* __restrict__ cur_cn, int* __restrict__ cur_ce,
                         int* __restrict__ csr_cn, int* __restrict__ csr_ce,
                         int nnz, int n, int e) {
    int j = blockIdx.x * blockDim.x + threadIdx.x;
    if (j < nnz) {
        int v = ni[j], eg = ei[j];
        int be = bucket_of(eg, e);
        int pe = atomicAdd(&bcur_e[be], 1);
        stg_e[pe] = (u32)v | ((u32)eg << 16);    // v<65536, eg<16384
        int bn = bucket_of(v, n);
        int pn = atomicAdd(&bcur_n[bn], 1);
        stg_n[pn] = (u32)eg | ((u32)v << 14);    // eg<16384
    }
    if (j < n) { int c = nc_c[j]; csr_cn[atomicAdd(&cur_cn[c], 1)] = nc_n[j]; }
    if (j < e) { int c = ec_c[j]; csr_ce[atomicAdd(&cur_ce[c], 1)] = ec_e[j]; }
}

// ---------- phase B: per-bucket reorder into CSR (LDS counters, local writes) ----------
__global__ __launch_bounds__(256) void k_scat_b(
        const u32* __restrict__ stg_e, const u32* __restrict__ stg_n,
        const int* __restrict__ off_e, const int* __restrict__ off_n,
        int* __restrict__ csr_e, int* __restrict__ csr_n, int e, int n) {
    __shared__ int lcnt[LCNT];
    int b = blockIdx.x;
    const u32* stg; const int* off; int* csr; int total;
    if (b < KB) { stg = stg_e; off = off_e; csr = csr_e; total = e; }
    else        { stg = stg_n; off = off_n; csr = csr_n; total = n; b -= KB; }
    int lo = bstart(b, total), hi = bstart(b + 1, total);
    int nid = hi - lo;
    for (int t = threadIdx.x; t < nid; t += 256) lcnt[t] = off[lo + t];
    __syncthreads();
    int s0 = off[lo], s1 = off[hi];
    if (total == e) {
        for (int i = s0 + threadIdx.x; i < s1; i += 256) {
            u32 s = stg[i];
            int eg = (int)(s >> 16), v = (int)(s & 0xFFFFu);
            int p = atomicAdd(&lcnt[eg - lo], 1);
            csr[p] = v;
        }
    } else {
        for (int i = s0 + threadIdx.x; i < s1; i += 256) {
            u32 s = stg[i];
            int v = (int)(s >> 14), eg = (int)(s & 0x3FFFu);
            int p = atomicAdd(&lcnt[v - lo], 1);
            csr[p] = eg;
        }
    }
}

// ---------- fallback scatter (generality guard) ----------
__global__ void k_scatter(const int* __restrict__ ni, const int* __restrict__ ei,
                          const int* __restrict__ nc_n, const int* __restrict__ nc_c,
                          const int* __restrict__ ec_e, const int* __restrict__ ec_c,
                          int* __restrict__ cur_e, int* __restrict__ cur_n,
                          int* __restrict__ cur_cn, int* __restrict__ cur_ce,
                          int* __restrict__ csr_e, int* __restrict__ csr_n,
                          int* __restrict__ csr_cn, int* __restrict__ csr_ce,
                          int nnz, int n, int e) {
    int j = blockIdx.x * blockDim.x + threadIdx.x;
    if (j < nnz) {
        int v = ni[j], eg = ei[j];
        csr_e[atomicAdd(&cur_e[eg], 1)] = v;
        csr_n[atomicAdd(&cur_n[v], 1)] = eg;
    }
    if (j < n) { int c = nc_c[j]; csr_cn[atomicAdd(&cur_cn[c], 1)] = nc_n[j]; }
    if (j < e) { int c = ec_c[j]; csr_ce[atomicAdd(&cur_ce[c], 1)] = ec_e[j]; }
}

// ---------- segment mean: wave per segment, 4 rows per load instruction ----------
__device__ __forceinline__ void agg4_body(const u32* __restrict__ in,
                                          const int* __restrict__ items,
                                          const int* __restrict__ off,
                                          float* __restrict__ out_f32,
                                          u32* __restrict__ out_bf,
                                          int nseg, int nrows, int do_prelu,
                                          const float* __restrict__ alpha_p, int seg) {
    int lane = threadIdx.x & 63;
    int rs = lane >> 4;        // row slot 0..3
    int cc = lane & 15;        // col chunk (uint4 index within row)
    if (seg >= nseg) return;
    int s0 = off[seg], s1 = off[seg + 1];
    const uint4* rows = (const uint4*)in;
    float a[8];
#pragma unroll
    for (int i = 0; i < 8; ++i) a[i] = 0.f;
    int base = s0;
    for (; base + 8 <= s1; base += 8) {
        u32 r0 = (u32)items[base + rs];
        u32 r1 = (u32)items[base + 4 + rs];
        r0 = (r0 < (u32)nrows) ? r0 : 0u;
        r1 = (r1 < (u32)nrows) ? r1 : 0u;
        uint4 v0 = rows[(size_t)r0 * 16 + cc];
        uint4 v1 = rows[(size_t)r1 * 16 + cc];
        a[0] += bflo(v0.x); a[1] += bfhi(v0.x); a[2] += bflo(v0.y); a[3] += bfhi(v0.y);
        a[4] += bflo(v0.z); a[5] += bfhi(v0.z); a[6] += bflo(v0.w); a[7] += bfhi(v0.w);
        a[0] += bflo(v1.x); a[1] += bfhi(v1.x); a[2] += bflo(v1.y); a[3] += bfhi(v1.y);
        a[4] += bflo(v1.z); a[5] += bfhi(v1.z); a[6] += bflo(v1.w); a[7] += bfhi(v1.w);
    }
    int idx = base + rs;
    if (idx < s1) {
        u32 r = (u32)items[idx]; r = (r < (u32)nrows) ? r : 0u;
        uint4 v = rows[(size_t)r * 16 + cc];
        a[0] += bflo(v.x); a[1] += bfhi(v.x); a[2] += bflo(v.y); a[3] += bfhi(v.y);
        a[4] += bflo(v.z); a[5] += bfhi(v.z); a[6] += bflo(v.w); a[7] += bfhi(v.w);
    }
    idx += 4;
    if (idx < s1) {
        u32 r = (u32)items[idx]; r = (r < (u32)nrows) ? r : 0u;
        uint4 v = rows[(size_t)r * 16 + cc];
        a[0] += bflo(v.x); a[1] += bfhi(v.x); a[2] += bflo(v.y); a[3] += bfhi(v.y);
        a[4] += bflo(v.z); a[5] += bfhi(v.z); a[6] += bflo(v.w); a[7] += bfhi(v.w);
    }
#pragma unroll
    for (int i = 0; i < 8; ++i) {
        a[i] += __shfl_xor(a[i], 16, 64);
        a[i] += __shfl_xor(a[i], 32, 64);
    }
    float inv = 1.f / fmaxf((float)(s1 - s0), 1.f);
#pragma unroll
    for (int i = 0; i < 8; ++i) a[i] *= inv;
    if (do_prelu) {
        float al = *alpha_p;
#pragma unroll
        for (int i = 0; i < 8; ++i) a[i] = (a[i] >= 0.f) ? a[i] : al * a[i];
    }
    if (rs == 0) {
        if (out_f32) {
            float* o = out_f32 + ((size_t)seg << 7) + cc * 8;
            *(float4*)o       = make_float4(a[0], a[1], a[2], a[3]);
            *(float4*)(o + 4) = make_float4(a[4], a[5], a[6], a[7]);
        }
        if (out_bf) {
            uint4 pk;
            pk.x = pack2(a[0], a[1]); pk.y = pack2(a[2], a[3]);
            pk.z = pack2(a[4], a[5]); pk.w = pack2(a[6], a[7]);
            *(uint4*)(out_bf + ((size_t)seg << 6) + cc * 4) = pk;
        }
    }
}

__global__ void k_agg4(const u32* __restrict__ in, const int* __restrict__ items,
                       const int* __restrict__ off, float* __restrict__ out_f32,
                       u32* __restrict__ out_bf,
                       int nseg, int nrows, int do_prelu, const float* __restrict__ alpha_p) {
    int seg = blockIdx.x * (blockDim.x >> 6) + (threadIdx.x >> 6);
    agg4_body(in, items, off, out_f32, out_bf, nseg, nrows, do_prelu, alpha_p, seg);
}

__global__ void k_agg_c2(const u32* inA, const int* itemsA, const int* offA, float* outA, int nrowsA,
                         const u32* inB, const int* itemsB, const int* offB, float* outB, int nrowsB,
                         int nseg) {
    int seg = blockIdx.x * (blockDim.x >> 6) + (threadIdx.x >> 6);
    if (blockIdx.y == 0) agg4_body(inA, itemsA, offA, outA, nullptr, nseg, nrowsA, 0, nullptr, seg);
    else                 agg4_body(inB, itemsB, offB, outB, nullptr, nseg, nrowsB, 0, nullptr, seg);
}

// ---------- fused 2-layer MLP ----------
__global__ __launch_bounds__(256) void k_mlp(
        const float* __restrict__ A, const float* __restrict__ W1,
        const float* __restrict__ W2,
        float* __restrict__ out_raw, u32* __restrict__ out_actbf,
        u32* __restrict__ out_ybf,
        int M, const float* __restrict__ alpha_p) {
    __shared__ float As[32 * 132];
    __shared__ float Ws[128 * 64];
    int t  = threadIdx.x;
    int rb = blockIdx.x * 32;
    int cg = t & 7, rg = t >> 3;
    int row = rb + rg;

    for (int i = t; i < 32 * 32; i += 256) {
        int r = i >> 5, dc = i & 31;
        int arow = rb + r;
        float4 v = make_float4(0.f, 0.f, 0.f, 0.f);
        if (arow < M) v = *(const float4*)(A + ((size_t)arow << 7) + dc * 4);
        *(float4*)&As[r * 132 + dc * 4] = v;
    }

    float e[2][8];
#pragma unroll
    for (int h = 0; h < 2; ++h) {
        __syncthreads();
        for (int i = t; i < 128 * 16; i += 256) {
            int k = i >> 4, dc = i & 15;
            *(float4*)&Ws[k * 64 + dc * 4] = *(const float4*)(W1 + ((size_t)k << 7) + h * 64 + dc * 4);
        }
        __syncthreads();
        float acc[8];
#pragma unroll
        for (int i = 0; i < 8; ++i) acc[i] = 0.f;
        for (int k = 0; k < 128; ++k) {
            float av = As[rg * 132 + k];
            float4 w0 = *(const float4*)&Ws[k * 64 + cg * 8];
            float4 w1 = *(const float4*)&Ws[k * 64 + cg * 8 + 4];
            acc[0] += av * w0.x; acc[1] += av * w0.y; acc[2] += av * w0.z; acc[3] += av * w0.w;
            acc[4] += av * w1.x; acc[5] += av * w1.y; acc[6] += av * w1.z; acc[7] += av * w1.w;
        }
#pragma unroll
        for (int i = 0; i < 8; ++i) e[h][i] = acc[i];
    }
    __syncthreads();

    float al = *alpha_p;
    if (row < M && out_raw) {
#pragma unroll
        for (int h = 0; h < 2; ++h) {
            float* o = out_raw + ((size_t)row << 7) + h * 64 + cg * 8;
            *(float4*)o       = make_float4(e[h][0], e[h][1], e[h][2], e[h][3]);
            *(float4*)(o + 4) = make_float4(e[h][4], e[h][5], e[h][6], e[h][7]);
        }
    }
    float act[2][8];
#pragma unroll
    for (int h = 0; h < 2; ++h)
#pragma unroll
        for (int i = 0; i < 8; ++i) { float x = e[h][i]; act[h][i] = (x >= 0.f) ? x : al * x; }
    if (row < M && out_actbf) {
#pragma unroll
        for (int h = 0; h < 2; ++h) {
            uint4 pk;
            pk.x = pack2(act[h][0], act[h][1]); pk.y = pack2(act[h][2], act[h][3]);
            pk.z = pack2(act[h][4], act[h][5]); pk.w = pack2(act[h][6], act[h][7]);
            *(uint4*)(out_actbf + ((size_t)row << 6) + h * 32 + cg * 4) = pk;
        }
    }
#pragma unroll
    for (int h = 0; h < 2; ++h) {
        *(float4*)&As[rg * 132 + h * 64 + cg * 8]     = make_float4(act[h][0], act[h][1], act[h][2], act[h][3]);
        *(float4*)&As[rg * 132 + h * 64 + cg * 8 + 4] = make_float4(act[h][4], act[h][5], act[h][6], act[h][7]);
    }

    float y[2][8];
#pragma unroll
    for (int h = 0; h < 2; ++h) {
        __syncthreads();
        for (int i = t; i < 128 * 16; i += 256) {
            int k = i >> 4, dc = i & 15;
            *(float4*)&Ws[k * 64 + dc * 4] = *(const float4*)(W2 + ((size_t)k << 7) + h * 64 + dc * 4);
        }
        __syncthreads();
        float acc[8];
#pragma unroll
        for (int i = 0; i < 8; ++i) acc[i] = 0.f;
        for (int k = 0; k < 128; ++k) {
            float av = As[rg * 132 + k];
            float4 w0 = *(const float4*)&Ws[k * 64 + cg * 8];
            float4 w1 = *(const float4*)&Ws[k * 64 + cg * 8 + 4];
            acc[0] += av * w0.x; acc[1] += av * w0.y; acc[2] += av * w0.z; acc[3] += av * w0.w;
            acc[4] += av * w1.x; acc[5] += av * w1.y; acc[6] += av * w1.z; acc[7] += av * w1.w;
        }
#pragma unroll
        for (int i = 0; i < 8; ++i) y[h][i] = acc[i];
    }
    if (row < M && out_ybf) {
#pragma unroll
        for (int h = 0; h < 2; ++h) {
            uint4 pk;
            pk.x = pack2(y[h][0], y[h][1]); pk.y = pack2(y[h][2], y[h][3]);
            pk.z = pack2(y[h][4], y[h][5]); pk.w = pack2(y[h][6], y[h][7]);
            *(uint4*)(out_ybf + ((size_t)row << 6) + h * 32 + cg * 4) = pk;
        }
    }
}

// ---------- component GEMM: pair-accumulate [C,128]@[128,128] ----------
__global__ __launch_bounds__(256) void k_gemm128(
        const float* __restrict__ A,  const float* __restrict__ W,
        const float* __restrict__ A2, const float* __restrict__ W2,
        float* __restrict__ out_raw,
        int M, const float* __restrict__ alpha_p) {
    __shared__ float As[64 * 128];
    __shared__ float Ws[128 * 64];
    int t  = threadIdx.x;
    int rb = blockIdx.x * 64;
    int cb = blockIdx.y * 64;
    int cg = t & 7, rg = t >> 3;
    int c0 = cg * 8;
    int sw = (rg & 7) << 2;

    float acc[16];
#pragma unroll
    for (int i = 0; i < 16; ++i) acc[i] = 0.f;

    for (int pair = 0; pair < 2; ++pair) {
        const float* Ap = pair ? A2 : A;
        const float* Wp = pair ? W2 : W;
        if (pair) __syncthreads();
        for (int i = t; i < 64 * 32; i += 256) {
            int r = i >> 5, dc = i & 31;
            int row = rb + r;
            float4 v = make_float4(0.f, 0.f, 0.f, 0.f);
            if (row < M) v = *(const float4*)(Ap + ((size_t)row << 7) + dc * 4);
            int swr = (r & 7) << 2;
            *(float4*)&As[r * 128 + ((dc * 4) ^ swr)] = v;
        }
        for (int i = t; i < 128 * 16; i += 256) {
            int k = i >> 4, dc = i & 15;
            *(float4*)&Ws[k * 64 + dc * 4] = *(const float4*)(Wp + ((size_t)k << 7) + cb + dc * 4);
        }
        __syncthreads();
#pragma unroll 4
        for (int k = 0; k < 128; ++k) {
            float a0 = As[rg * 128 + (k ^ sw)];
            float a1 = As[(rg + 32) * 128 + (k ^ sw)];
            const float* wr = &Ws[k * 64 + c0];
            float4 w0 = *(const float4*)(wr);
            float4 w1 = *(const float4*)(wr + 4);
            acc[0]  += a0 * w0.x; acc[1]  += a0 * w0.y; acc[2]  += a0 * w0.z; acc[3]  += a0 * w0.w;
            acc[4]  += a0 * w1.x; acc[5]  += a0 * w1.y; acc[6]  += a0 * w1.z; acc[7]  += a0 * w1.w;
            acc[8]  += a1 * w0.x; acc[9]  += a1 * w0.y; acc[10] += a1 * w0.z; acc[11] += a1 * w0.w;
            acc[12] += a1 * w1.x; acc[13] += a1 * w1.y; acc[14] += a1 * w1.z; acc[15] += a1 * w1.w;
        }
    }
#pragma unroll
    for (int h = 0; h < 2; ++h) {
        int row = rb + rg + h * 32;
        if (row >= M) continue;
        size_t ob = ((size_t)row << 7) + cb + c0;
        *(float4*)(out_raw + ob)     = make_float4(acc[h*8+0], acc[h*8+1], acc[h*8+2], acc[h*8+3]);
        *(float4*)(out_raw + ob + 4) = make_float4(acc[h*8+4], acc[h*8+5], acc[h*8+6], acc[h*8+7]);
    }
}

extern "C" void kernel_launch(void* const* d_in, const int* in_sizes, int n_in,
                              void* d_out, int out_size, void* d_ws, size_t ws_size,
                              hipStream_t stream) {
    const int N   = in_sizes[0] / 128;   // 50000
    const int NNZ = in_sizes[1] / 2;     // 400000
    const int E   = in_sizes[2] / 2;     // 10000
    const int C   = 500;

    const float* x0 = (const float*)d_in[0];
    const int* ni   = (const int*)d_in[1];
    const int* ei   = ni + NNZ;
    const int* ec_e = (const int*)d_in[2];
    const int* ec_c = ec_e + E;
    const int* nc_n = (const int*)d_in[3];
    const int* nc_c = nc_n + N;
    const float* Wne0 = (const float*)d_in[7];
    const float* Wen0 = (const float*)d_in[8];
    const float* Wne1 = (const float*)d_in[11];
    const float* Wen1 = (const float*)d_in[12];
    const float* Wec1 = (const float*)d_in[13];
    const float* Wnc1 = (const float*)d_in[14];
    const float* alpha = (const float*)d_in[15];

    float* out_x = (float*)d_out;                 // [N,128]
    float* out_e = out_x + (size_t)N * 128;       // [E,128]
    float* out_c = out_e + (size_t)E * 128;       // [C,128]

    // ---- carve workspace ----
    char* w = (char*)d_ws;
    auto alloc = [&](size_t bytes) { char* p = w; w += (bytes + 255) & ~(size_t)255; return p; };
    int* counters = (int*)alloc((size_t)(E + N + 2 * C) * 4);
    int* deg_e  = counters;
    int* deg_n  = counters + E;
    int* cnt_cn = counters + E + N;
    int* cnt_ce = counters + E + N + C;
    int* off_e  = (int*)alloc((size_t)(E + 1) * 4);
    int* off_n  = (int*)alloc((size_t)(N + 1) * 4);
    int* off_cn = (int*)alloc((size_t)(C + 1) * 4);
    int* off_ce = (int*)alloc((size_t)(C + 1) * 4);
    int* cur_e  = (int*)alloc((size_t)E * 4);
    int* cur_n  = (int*)alloc((size_t)N * 4);
    int* cur_cn = (int*)alloc((size_t)C * 4);
    int* cur_ce = (int*)alloc((size_t)C * 4);
    int* csr_e  = (int*)alloc((size_t)NNZ * 4);
    int* csr_n  = (int*)alloc((size_t)NNZ * 4);
    int* csr_cn = (int*)alloc((size_t)N * 4);
    int* csr_ce = (int*)alloc((size_t)E * 4);
    int* tilesum  = (int*)alloc(64 * 4);
    int* tilebase = (int*)alloc(64 * 4);
    int* bcur_e = (int*)alloc(KB * 4);
    int* bcur_n = (int*)alloc(KB * 4);
    u32* stg_e  = (u32*)alloc((size_t)NNZ * 4);
    u32* stg_n  = (u32*)alloc((size_t)NNZ * 4);
    u32* xbf    = (u32*)alloc((size_t)N * 64 * 4);
    u32* x1bf   = (u32*)alloc((size_t)N * 64 * 4);
    u32* ybf    = (u32*)alloc((size_t)E * 64 * 4);
    u32* eactbf = (u32*)alloc((size_t)E * 64 * 4);
    float* xa   = (float*)alloc((size_t)E * 128 * 4);
    float* ca_e = (float*)alloc((size_t)C * 128 * 4);
    float* ca_n = (float*)alloc((size_t)C * 128 * 4);

    const int th = 256;
    const int t0 = (E + TS - 1) / TS;
    const int t1 = (N + TS - 1) / TS;
    const int t2 = (C + TS - 1) / TS;
    const int t3 = (C + TS - 1) / TS;
    const int t01 = t0 + t1, t012 = t01 + t2, t0123 = t012 + t3;
    const int npairs = N * 64;

    // ---- CSR build + x conversion ----
    hipMemsetAsync(counters, 0, (size_t)(E + N + 2 * C) * 4, stream);
    k_hist_cvt<<<(npairs + th - 1) / th, th, 0, stream>>>(
        (const float2*)x0, xbf, npairs, ni, ei, nc_c, ec_c,
        deg_e, deg_n, cnt_cn, cnt_ce, NNZ, N, E);
    k_scan_p1<<<t0123, 256, 0, stream>>>(deg_e, E, deg_n, N, cnt_cn, C, cnt_ce, C,
                                         t0, t01, t012, tilesum);
    k_scan_p2<<<1, 64, 0, stream>>>(tilesum, tilebase, t0, t01, t012, t0123,
                                    off_e, E, off_n, N, off_cn, C, off_ce, C);
    k_scan_p3<<<t0123, 256, 0, stream>>>(deg_e, off_e, cur_e, E,
                                         deg_n, off_n, cur_n, N,
                                         cnt_cn, off_cn, cur_cn, C,
                                         cnt_ce, off_ce, cur_ce, C,
                                         t0, t01, t012, tilebase);
    bool binned = (E <= 16384) && (N <= 65536) &&
                  ((E + KB - 1) / KB < LCNT) && ((N + KB - 1) / KB < LCNT) &&
                  (E >= KB) && (N >= KB);
    if (binned) {
        k_binit<<<2, 1024, 0, stream>>>(off_e, off_n, bcur_e, bcur_n, E, N);
        k_scat_a<<<(NNZ + th - 1) / th, th, 0, stream>>>(ni, ei, nc_n, nc_c, ec_e, ec_c,
                                                         bcur_e, bcur_n, stg_e, stg_n,
                                                         cur_cn, cur_ce, csr_cn, csr_ce, NNZ, N, E);
        k_scat_b<<<2 * KB, 256, 0, stream>>>(stg_e, stg_n, off_e, off_n, csr_e, csr_n, E, N);
    } else {
        k_scatter<<<(NNZ + th - 1) / th, th, 0, stream>>>(ni, ei, nc_n, nc_c, ec_e, ec_c,
                                                          cur_e, cur_n, cur_cn, cur_ce,
                                                          csr_e, csr_n, csr_cn, csr_ce, NNZ, N, E);
    }

    const int gmlp = (E + 31) / 32;
    // ---- layer 1 ----
    k_agg4<<<(E + 3) / 4, 256, 0, stream>>>(xbf, csr_e, off_e, xa, nullptr, E, N, 0, alpha);
    k_mlp<<<gmlp, 256, 0, stream>>>(xa, Wne0, Wen0, nullptr, nullptr, ybf, E, alpha);
    k_agg4<<<(N + 3) / 4, 256, 0, stream>>>(ybf, csr_n, off_n, nullptr, x1bf, N, E, 1, alpha);
    // ---- layer 2 ----
    k_agg4<<<(E + 3) / 4, 256, 0, stream>>>(x1bf, csr_e, off_e, xa, nullptr, E, N, 0, alpha);
    k_mlp<<<gmlp, 256, 0, stream>>>(xa, Wne1, Wen1, out_e, eactbf, ybf, E, alpha);
    // ---- components ----
    {
        dim3 gC2((C + 3) / 4, 2);
        k_agg_c2<<<gC2, 256, 0, stream>>>(eactbf, csr_ce, off_ce, ca_e, E,
                                          x1bf,   csr_cn, off_cn, ca_n, N, C);
    }
    {
        dim3 gC((C + 63) / 64, 2);
        k_gemm128<<<gC, 256, 0, stream>>>(ca_e, Wec1, ca_n, Wnc1, out_c, C, alpha);
    }
    // ---- node output ----
    k_agg4<<<(N + 3) / 4, 256, 0, stream>>>(ybf, csr_n, off_n, out_x, nullptr, N, E, 1, alpha);
}

// Round 8
// 370.959 us; speedup vs baseline: 1.2907x; 1.2907x over previous
//
#include <hip/hip_runtime.h>
#include <stdint.h>

typedef unsigned int u32;
#define TS 4096     // scan tile size (256 thr x 16)
#define KB2 256     // partition buckets per side
#define CH 2048     // entries per phase-A block

// ---------- bf16 helpers ----------
__device__ __forceinline__ float bflo(u32 u) { return __uint_as_float(u << 16); }
__device__ __forceinline__ float bfhi(u32 u) { return __uint_as_float(u & 0xffff0000u); }
__device__ __forceinline__ u32 f2bf(float x) {
    u32 u = __float_as_uint(x);
    return (u + 0x7fffu + ((u >> 16) & 1u)) >> 16;   // RNE
}
__device__ __forceinline__ u32 pack2(float a, float b) { return f2bf(a) | (f2bf(b) << 16); }

__device__ __forceinline__ int bstart2(int b, int total) {
    return (int)(((unsigned long long)b * (u32)total + KB2 - 1) / KB2);
}

// ---------- fused histogram + x->bf16 conversion ----------
__global__ void k_hist_cvt(const float2* __restrict__ x0, u32* __restrict__ xbf, int npairs,
                           const int* __restrict__ ni, const int* __restrict__ ei,
                           const int* __restrict__ nc_c, const int* __restrict__ ec_c,
                           int* __restrict__ deg_e, int* __restrict__ deg_n,
                           int* __restrict__ cnt_cn, int* __restrict__ cnt_ce,
                           int nnz, int n, int e) {
    int j = blockIdx.x * blockDim.x + threadIdx.x;
    if (j < npairs) { float2 v = x0[j]; xbf[j] = pack2(v.x, v.y); }
    if (j < nnz) {
        atomicAdd(&deg_e[ei[j]], 1);
        atomicAdd(&deg_n[ni[j]], 1);
    }
    if (j < n) atomicAdd(&cnt_cn[nc_c[j]], 1);
    if (j < e) atomicAdd(&cnt_ce[ec_c[j]], 1);
}

// ---------- 3-phase parallel exclusive scan over 4 arrays ----------
__device__ __forceinline__ void scan_sel(int b, int t0, int t01, int t012,
        const int* c0, int* o0, int* u0, int n0,
        const int* c1, int* o1, int* u1, int n1,
        const int* c2, int* o2, int* u2, int n2,
        const int* c3, int* o3, int* u3, int n3,
        const int*& cnt, int*& off, int*& cur, int& n, int& tile) {
    if (b < t0)        { cnt = c0; off = o0; cur = u0; n = n0; tile = b; }
    else if (b < t01)  { cnt = c1; off = o1; cur = u1; n = n1; tile = b - t0; }
    else if (b < t012) { cnt = c2; off = o2; cur = u2; n = n2; tile = b - t01; }
    else               { cnt = c3; off = o3; cur = u3; n = n3; tile = b - t012; }
}

__global__ void k_scan_p1(const int* c0, int n0, const int* c1, int n1,
                          const int* c2, int n2, const int* c3, int n3,
                          int t0, int t01, int t012, int* __restrict__ tilesum) {
    __shared__ int ws[4];
    int b = blockIdx.x;
    const int* cnt; int* off; int* cur; int n; int tile;
    scan_sel(b, t0, t01, t012, c0, nullptr, nullptr, n0, c1, nullptr, nullptr, n1,
             c2, nullptr, nullptr, n2, c3, nullptr, nullptr, n3, cnt, off, cur, n, tile);
    int base = tile * TS + threadIdx.x * 16;
    int s = 0;
#pragma unroll
    for (int i = 0; i < 16; ++i) { int idx = base + i; if (idx < n) s += cnt[idx]; }
    for (int d = 32; d; d >>= 1) s += __shfl_xor(s, d, 64);
    int lane = threadIdx.x & 63, w = threadIdx.x >> 6;
    if (lane == 0) ws[w] = s;
    __syncthreads();
    if (threadIdx.x == 0) tilesum[b] = ws[0] + ws[1] + ws[2] + ws[3];
}

__global__ void k_scan_p2(const int* __restrict__ tilesum, int* __restrict__ tilebase,
                          int t0, int t01, int t012, int t0123,
                          int* o0, int n0, int* o1, int n1, int* o2, int n2, int* o3, int n3) {
    if (threadIdx.x != 0 || blockIdx.x != 0) return;
    int carry = 0;
    for (int b = 0;    b < t0;    ++b) { tilebase[b] = carry; carry += tilesum[b]; } o0[n0] = carry;
    carry = 0;
    for (int b = t0;   b < t01;   ++b) { tilebase[b] = carry; carry += tilesum[b]; } o1[n1] = carry;
    carry = 0;
    for (int b = t01;  b < t012;  ++b) { tilebase[b] = carry; carry += tilesum[b]; } o2[n2] = carry;
    carry = 0;
    for (int b = t012; b < t0123; ++b) { tilebase[b] = carry; carry += tilesum[b]; } o3[n3] = carry;
}

__global__ void k_scan_p3(const int* c0, int* o0, int* u0, int n0,
                          const int* c1, int* o1, int* u1, int n1,
                          const int* c2, int* o2, int* u2, int n2,
                          const int* c3, int* o3, int* u3, int n3,
                          int t0, int t01, int t012, const int* __restrict__ tilebase) {
    __shared__ int wsum[4];
    int b = blockIdx.x;
    const int* cnt; int* off; int* cur; int n; int tile;
    scan_sel(b, t0, t01, t012, c0, o0, u0, n0, c1, o1, u1, n1,
             c2, o2, u2, n2, c3, o3, u3, n3, cnt, off, cur, n, tile);
    int lane = threadIdx.x & 63, w = threadIdx.x >> 6;
    int base = tile * TS + threadIdx.x * 16;
    int vals[16];
    int s = 0;
#pragma unroll
    for (int i = 0; i < 16; ++i) { int idx = base + i; int v = (idx < n) ? cnt[idx] : 0; vals[i] = v; s += v; }
    int inc = s;
    for (int d = 1; d < 64; d <<= 1) { int u = __shfl_up(inc, d, 64); if (lane >= d) inc += u; }
    if (lane == 63) wsum[w] = inc;
    __syncthreads();
    if (threadIdx.x == 0) {
        int acc = tilebase[b];
        for (int i = 0; i < 4; ++i) { int t = wsum[i]; wsum[i] = acc; acc += t; }
    }
    __syncthreads();
    int ex = wsum[w] + (inc - s);
#pragma unroll
    for (int i = 0; i < 16; ++i) {
        int idx = base + i;
        if (idx < n) { off[idx] = ex; cur[idx] = ex; }
        ex += vals[i];
    }
}

// ---------- bucket cursor init ----------
__global__ void k_binit(const int* __restrict__ off_e, const int* __restrict__ off_n,
                        int* __restrict__ bcur_e, int* __restrict__ bcur_n, int e, int n) {
    int t = blockIdx.x * blockDim.x + threadIdx.x;
    if (t < KB2) bcur_e[t] = off_e[bstart2(t, e)];
    else if (t < 2 * KB2) { int b = t - KB2; bcur_n[b] = off_n[bstart2(b, n)]; }
}

// ---------- phase A: LDS radix partition into bucket-contiguous staging ----------
// Per-entry atomics are LDS-only; global atomics = one reservation per (block,bucket).
__global__ __launch_bounds__(256) void k_part_a(
        const int* __restrict__ ni, const int* __restrict__ ei,
        int* __restrict__ bcur_e, int* __restrict__ bcur_n,
        u32* __restrict__ stg_e, u32* __restrict__ stg_n,
        int nnz, int n, int e) {
    __shared__ u32 pk[CH];
    __shared__ unsigned short bb[CH];
    __shared__ int hist[KB2];
    __shared__ int gb[KB2];
    int side = blockIdx.y;                 // 0: edge-keyed, 1: node-keyed
    int base = blockIdx.x * CH;
    int cnt  = nnz - base; if (cnt > CH) cnt = CH;
    int t = threadIdx.x;
    for (int i = t; i < KB2; i += 256) hist[i] = 0;
    __syncthreads();
    u32 total = side ? (u32)n : (u32)e;
    for (int i = t; i < cnt; i += 256) {
        int v = ni[base + i], eg = ei[base + i];
        u32 key = side ? (u32)v : (u32)eg;
        u32 pay = side ? (u32)eg : (u32)v;
        if (key >= total) key = 0;
        u32 b = (u32)(((unsigned long long)key * KB2) / total);
        pk[i] = side ? (pay | (key << 14)) : (pay | (key << 16));
        bb[i] = (unsigned short)b;
        atomicAdd(&hist[b], 1);
    }
    __syncthreads();
    int* cursor = side ? bcur_n : bcur_e;
    u32* stg    = side ? stg_n  : stg_e;
    if (t < KB2) {
        int h = hist[t];
        gb[t] = h ? atomicAdd(&cursor[t], h) : 0;
        hist[t] = 0;
    }
    __syncthreads();
    for (int i = t; i < cnt; i += 256) {
        int b = bb[i];
        int r = atomicAdd(&hist[b], 1);
        stg[gb[b] + r] = pk[i];
    }
}

// ---------- phase B: per-bucket reorder into CSR (LDS counters, local writes) ----------
__global__ __launch_bounds__(256) void k_part_b(
        const u32* __restrict__ stg_e, const u32* __restrict__ stg_n,
        const int* __restrict__ off_e, const int* __restrict__ off_n,
        int* __restrict__ csr_e, int* __restrict__ csr_n, int e, int n) {
    __shared__ int lcnt[256];
    int b = blockIdx.x;
    const u32* stg; const int* off; int* csr; int total; int side;
    if (b < KB2) { stg = stg_e; off = off_e; csr = csr_e; total = e; side = 0; }
    else { b -= KB2; stg = stg_n; off = off_n; csr = csr_n; total = n; side = 1; }
    int lo = bstart2(b, total), hi = bstart2(b + 1, total);
    int nid = hi - lo;
    for (int t = threadIdx.x; t < nid; t += 256) lcnt[t] = off[lo + t];
    __syncthreads();
    int s0 = off[lo], s1 = off[hi];
    if (side == 0) {
        for (int i = s0 + threadIdx.x; i < s1; i += 256) {
            u32 s = stg[i];
            int key = (int)(s >> 16), pay = (int)(s & 0xFFFFu);
            int p = atomicAdd(&lcnt[key - lo], 1);
            csr[p] = pay;
        }
    } else {
        for (int i = s0 + threadIdx.x; i < s1; i += 256) {
            u32 s = stg[i];
            int key = (int)(s >> 14), pay = (int)(s & 0x3FFFu);
            int p = atomicAdd(&lcnt[key - lo], 1);
            csr[p] = pay;
        }
    }
}

// ---------- component scatter (small: N+E entries) ----------
__global__ void k_scat_comp(const int* __restrict__ nc_n, const int* __restrict__ nc_c,
                            const int* __restrict__ ec_e, const int* __restrict__ ec_c,
                            int* __restrict__ cur_cn, int* __restrict__ cur_ce,
                            int* __restrict__ csr_cn, int* __restrict__ csr_ce, int n, int e) {
    int j = blockIdx.x * blockDim.x + threadIdx.x;
    if (j < n) { int c = nc_c[j]; csr_cn[atomicAdd(&cur_cn[c], 1)] = nc_n[j]; }
    if (j < e) { int c = ec_c[j]; csr_ce[atomicAdd(&cur_ce[c], 1)] = ec_e[j]; }
}

// ---------- fallback scatter (generality guard; plain, no nt) ----------
__global__ void k_scatter(const int* __restrict__ ni, const int* __restrict__ ei,
                          const int* __restrict__ nc_n, const int* __restrict__ nc_c,
                          const int* __restrict__ ec_e, const int* __restrict__ ec_c,
                          int* __restrict__ cur_e, int* __restrict__ cur_n,
                          int* __restrict__ cur_cn, int* __restrict__ cur_ce,
                          int* __restrict__ csr_e, int* __restrict__ csr_n,
                          int* __restrict__ csr_cn, int* __restrict__ csr_ce,
                          int nnz, int n, int e) {
    int j = blockIdx.x * blockDim.x + threadIdx.x;
    if (j < nnz) {
        int v = ni[j], eg = ei[j];
        csr_e[atomicAdd(&cur_e[eg], 1)] = v;
        csr_n[atomicAdd(&cur_n[v], 1)] = eg;
    }
    if (j < n) { int c = nc_c[j]; csr_cn[atomicAdd(&cur_cn[c], 1)] = nc_n[j]; }
    if (j < e) { int c = ec_c[j]; csr_ce[atomicAdd(&cur_ce[c], 1)] = ec_e[j]; }
}

// ---------- segment mean: wave per segment, 4 rows per load instruction ----------
__device__ __forceinline__ void agg4_body(const u32* __restrict__ in,
                                          const int* __restrict__ items,
                                          const int* __restrict__ off,
                                          float* __restrict__ out_f32,
                                          u32* __restrict__ out_bf,
                                          int nseg, int nrows, int do_prelu,
                                          const float* __restrict__ alpha_p, int seg) {
    int lane = threadIdx.x & 63;
    int rs = lane >> 4;
    int cc = lane & 15;
    if (seg >= nseg) return;
    int s0 = off[seg], s1 = off[seg + 1];
    const uint4* rows = (const uint4*)in;
    float a[8];
#pragma unroll
    for (int i = 0; i < 8; ++i) a[i] = 0.f;
    int base = s0;
    for (; base + 8 <= s1; base += 8) {
        u32 r0 = (u32)items[base + rs];
        u32 r1 = (u32)items[base + 4 + rs];
        r0 = (r0 < (u32)nrows) ? r0 : 0u;
        r1 = (r1 < (u32)nrows) ? r1 : 0u;
        uint4 v0 = rows[(size_t)r0 * 16 + cc];
        uint4 v1 = rows[(size_t)r1 * 16 + cc];
        a[0] += bflo(v0.x); a[1] += bfhi(v0.x); a[2] += bflo(v0.y); a[3] += bfhi(v0.y);
        a[4] += bflo(v0.z); a[5] += bfhi(v0.z); a[6] += bflo(v0.w); a[7] += bfhi(v0.w);
        a[0] += bflo(v1.x); a[1] += bfhi(v1.x); a[2] += bflo(v1.y); a[3] += bfhi(v1.y);
        a[4] += bflo(v1.z); a[5] += bfhi(v1.z); a[6] += bflo(v1.w); a[7] += bfhi(v1.w);
    }
    int idx = base + rs;
    if (idx < s1) {
        u32 r = (u32)items[idx]; r = (r < (u32)nrows) ? r : 0u;
        uint4 v = rows[(size_t)r * 16 + cc];
        a[0] += bflo(v.x); a[1] += bfhi(v.x); a[2] += bflo(v.y); a[3] += bfhi(v.y);
        a[4] += bflo(v.z); a[5] += bfhi(v.z); a[6] += bflo(v.w); a[7] += bfhi(v.w);
    }
    idx += 4;
    if (idx < s1) {
        u32 r = (u32)items[idx]; r = (r < (u32)nrows) ? r : 0u;
        uint4 v = rows[(size_t)r * 16 + cc];
        a[0] += bflo(v.x); a[1] += bfhi(v.x); a[2] += bflo(v.y); a[3] += bfhi(v.y);
        a[4] += bflo(v.z); a[5] += bfhi(v.z); a[6] += bflo(v.w); a[7] += bfhi(v.w);
    }
#pragma unroll
    for (int i = 0; i < 8; ++i) {
        a[i] += __shfl_xor(a[i], 16, 64);
        a[i] += __shfl_xor(a[i], 32, 64);
    }
    float inv = 1.f / fmaxf((float)(s1 - s0), 1.f);
#pragma unroll
    for (int i = 0; i < 8; ++i) a[i] *= inv;
    if (do_prelu) {
        float al = *alpha_p;
#pragma unroll
        for (int i = 0; i < 8; ++i) a[i] = (a[i] >= 0.f) ? a[i] : al * a[i];
    }
    if (rs == 0) {
        if (out_f32) {
            float* o = out_f32 + ((size_t)seg << 7) + cc * 8;
            *(float4*)o       = make_float4(a[0], a[1], a[2], a[3]);
            *(float4*)(o + 4) = make_float4(a[4], a[5], a[6], a[7]);
        }
        if (out_bf) {
            uint4 pk;
            pk.x = pack2(a[0], a[1]); pk.y = pack2(a[2], a[3]);
            pk.z = pack2(a[4], a[5]); pk.w = pack2(a[6], a[7]);
            *(uint4*)(out_bf + ((size_t)seg << 6) + cc * 4) = pk;
        }
    }
}

__global__ void k_agg4(const u32* __restrict__ in, const int* __restrict__ items,
                       const int* __restrict__ off, float* __restrict__ out_f32,
                       u32* __restrict__ out_bf,
                       int nseg, int nrows, int do_prelu, const float* __restrict__ alpha_p) {
    int seg = blockIdx.x * (blockDim.x >> 6) + (threadIdx.x >> 6);
    agg4_body(in, items, off, out_f32, out_bf, nseg, nrows, do_prelu, alpha_p, seg);
}

__global__ void k_agg_c2(const u32* inA, const int* itemsA, const int* offA, float* outA, int nrowsA,
                         const u32* inB, const int* itemsB, const int* offB, float* outB, int nrowsB,
                         int nseg) {
    int seg = blockIdx.x * (blockDim.x >> 6) + (threadIdx.x >> 6);
    if (blockIdx.y == 0) agg4_body(inA, itemsA, offA, outA, nullptr, nseg, nrowsA, 0, nullptr, seg);
    else                 agg4_body(inB, itemsB, offB, outB, nullptr, nseg, nrowsB, 0, nullptr, seg);
}

// ---------- fused 2-layer MLP ----------
__global__ __launch_bounds__(256) void k_mlp(
        const float* __restrict__ A, const float* __restrict__ W1,
        const float* __restrict__ W2,
        float* __restrict__ out_raw, u32* __restrict__ out_actbf,
        u32* __restrict__ out_ybf,
        int M, const float* __restrict__ alpha_p) {
    __shared__ float As[32 * 132];
    __shared__ float Ws[128 * 64];
    int t  = threadIdx.x;
    int rb = blockIdx.x * 32;
    int cg = t & 7, rg = t >> 3;
    int row = rb + rg;

    for (int i = t; i < 32 * 32; i += 256) {
        int r = i >> 5, dc = i & 31;
        int arow = rb + r;
        float4 v = make_float4(0.f, 0.f, 0.f, 0.f);
        if (arow < M) v = *(const float4*)(A + ((size_t)arow << 7) + dc * 4);
        *(float4*)&As[r * 132 + dc * 4] = v;
    }

    float e[2][8];
#pragma unroll
    for (int h = 0; h < 2; ++h) {
        __syncthreads();
        for (int i = t; i < 128 * 16; i += 256) {
            int k = i >> 4, dc = i & 15;
            *(float4*)&Ws[k * 64 + dc * 4] = *(const float4*)(W1 + ((size_t)k << 7) + h * 64 + dc * 4);
        }
        __syncthreads();
        float acc[8];
#pragma unroll
        for (int i = 0; i < 8; ++i) acc[i] = 0.f;
        for (int k = 0; k < 128; ++k) {
            float av = As[rg * 132 + k];
            float4 w0 = *(const float4*)&Ws[k * 64 + cg * 8];
            float4 w1 = *(const float4*)&Ws[k * 64 + cg * 8 + 4];
            acc[0] += av * w0.x; acc[1] += av * w0.y; acc[2] += av * w0.z; acc[3] += av * w0.w;
            acc[4] += av * w1.x; acc[5] += av * w1.y; acc[6] += av * w1.z; acc[7] += av * w1.w;
        }
#pragma unroll
        for (int i = 0; i < 8; ++i) e[h][i] = acc[i];
    }
    __syncthreads();

    float al = *alpha_p;
    if (row < M && out_raw) {
#pragma unroll
        for (int h = 0; h < 2; ++h) {
            float* o = out_raw + ((size_t)row << 7) + h * 64 + cg * 8;
            *(float4*)o       = make_float4(e[h][0], e[h][1], e[h][2], e[h][3]);
            *(float4*)(o + 4) = make_float4(e[h][4], e[h][5], e[h][6], e[h][7]);
        }
    }
    float act[2][8];
#pragma unroll
    for (int h = 0; h < 2; ++h)
#pragma unroll
        for (int i = 0; i < 8; ++i) { float x = e[h][i]; act[h][i] = (x >= 0.f) ? x : al * x; }
    if (row < M && out_actbf) {
#pragma unroll
        for (int h = 0; h < 2; ++h) {
            uint4 pk;
            pk.x = pack2(act[h][0], act[h][1]); pk.y = pack2(act[h][2], act[h][3]);
            pk.z = pack2(act[h][4], act[h][5]); pk.w = pack2(act[h][6], act[h][7]);
            *(uint4*)(out_actbf + ((size_t)row << 6) + h * 32 + cg * 4) = pk;
        }
    }
#pragma unroll
    for (int h = 0; h < 2; ++h) {
        *(float4*)&As[rg * 132 + h * 64 + cg * 8]     = make_float4(act[h][0], act[h][1], act[h][2], act[h][3]);
        *(float4*)&As[rg * 132 + h * 64 + cg * 8 + 4] = make_float4(act[h][4], act[h][5], act[h][6], act[h][7]);
    }

    float y[2][8];
#pragma unroll
    for (int h = 0; h < 2; ++h) {
        __syncthreads();
        for (int i = t; i < 128 * 16; i += 256) {
            int k = i >> 4, dc = i & 15;
            *(float4*)&Ws[k * 64 + dc * 4] = *(const float4*)(W2 + ((size_t)k << 7) + h * 64 + dc * 4);
        }
        __syncthreads();
        float acc[8];
#pragma unroll
        for (int i = 0; i < 8; ++i) acc[i] = 0.f;
        for (int k = 0; k < 128; ++k) {
            float av = As[rg * 132 + k];
            float4 w0 = *(const float4*)&Ws[k * 64 + cg * 8];
            float4 w1 = *(const float4*)&Ws[k * 64 + cg * 8 + 4];
            acc[0] += av * w0.x; acc[1] += av * w0.y; acc[2] += av * w0.z; acc[3] += av * w0.w;
            acc[4] += av * w1.x; acc[5] += av * w1.y; acc[6] += av * w1.z; acc[7] += av * w1.w;
        }
#pragma unroll
        for (int i = 0; i < 8; ++i) y[h][i] = acc[i];
    }
    if (row < M && out_ybf) {
#pragma unroll
        for (int h = 0; h < 2; ++h) {
            uint4 pk;
            pk.x = pack2(y[h][0], y[h][1]); pk.y = pack2(y[h][2], y[h][3]);
            pk.z = pack2(y[h][4], y[h][5]); pk.w = pack2(y[h][6], y[h][7]);
            *(uint4*)(out_ybf + ((size_t)row << 6) + h * 32 + cg * 4) = pk;
        }
    }
}

// ---------- component GEMM: pair-accumulate [C,128]@[128,128] ----------
__global__ __launch_bounds__(256) void k_gemm128(
        const float* __restrict__ A,  const float* __restrict__ W,
        const float* __restrict__ A2, const float* __restrict__ W2,
        float* __restrict__ out_raw,
        int M, const float* __restrict__ alpha_p) {
    __shared__ float As[64 * 128];
    __shared__ float Ws[128 * 64];
    int t  = threadIdx.x;
    int rb = blockIdx.x * 64;
    int cb = blockIdx.y * 64;
    int cg = t & 7, rg = t >> 3;
    int c0 = cg * 8;
    int sw = (rg & 7) << 2;

    float acc[16];
#pragma unroll
    for (int i = 0; i < 16; ++i) acc[i] = 0.f;

    for (int pair = 0; pair < 2; ++pair) {
        const float* Ap = pair ? A2 : A;
        const float* Wp = pair ? W2 : W;
        if (pair) __syncthreads();
        for (int i = t; i < 64 * 32; i += 256) {
            int r = i >> 5, dc = i & 31;
            int row = rb + r;
            float4 v = make_float4(0.f, 0.f, 0.f, 0.f);
            if (row < M) v = *(const float4*)(Ap + ((size_t)row << 7) + dc * 4);
            int swr = (r & 7) << 2;
            *(float4*)&As[r * 128 + ((dc * 4) ^ swr)] = v;
        }
        for (int i = t; i < 128 * 16; i += 256) {
            int k = i >> 4, dc = i & 15;
            *(float4*)&Ws[k * 64 + dc * 4] = *(const float4*)(Wp + ((size_t)k << 7) + cb + dc * 4);
        }
        __syncthreads();
#pragma unroll 4
        for (int k = 0; k < 128; ++k) {
            float a0 = As[rg * 128 + (k ^ sw)];
            float a1 = As[(rg + 32) * 128 + (k ^ sw)];
            const float* wr = &Ws[k * 64 + c0];
            float4 w0 = *(const float4*)(wr);
            float4 w1 = *(const float4*)(wr + 4);
            acc[0]  += a0 * w0.x; acc[1]  += a0 * w0.y; acc[2]  += a0 * w0.z; acc[3]  += a0 * w0.w;
            acc[4]  += a0 * w1.x; acc[5]  += a0 * w1.y; acc[6]  += a0 * w1.z; acc[7]  += a0 * w1.w;
            acc[8]  += a1 * w0.x; acc[9]  += a1 * w0.y; acc[10] += a1 * w0.z; acc[11] += a1 * w0.w;
            acc[12] += a1 * w1.x; acc[13] += a1 * w1.y; acc[14] += a1 * w1.z; acc[15] += a1 * w1.w;
        }
    }
#pragma unroll
    for (int h = 0; h < 2; ++h) {
        int row = rb + rg + h * 32;
        if (row >= M) continue;
        size_t ob = ((size_t)row << 7) + cb + c0;
        *(float4*)(out_raw + ob)     = make_float4(acc[h*8+0], acc[h*8+1], acc[h*8+2], acc[h*8+3]);
        *(float4*)(out_raw + ob + 4) = make_float4(acc[h*8+4], acc[h*8+5], acc[h*8+6], acc[h*8+7]);
    }
}

extern "C" void kernel_launch(void* const* d_in, const int* in_sizes, int n_in,
                              void* d_out, int out_size, void* d_ws, size_t ws_size,
                              hipStream_t stream) {
    const int N   = in_sizes[0] / 128;   // 50000
    const int NNZ = in_sizes[1] / 2;     // 400000
    const int E   = in_sizes[2] / 2;     // 10000
    const int C   = 500;

    const float* x0 = (const float*)d_in[0];
    const int* ni   = (const int*)d_in[1];
    const int* ei   = ni + NNZ;
    const int* ec_e = (const int*)d_in[2];
    const int* ec_c = ec_e + E;
    const int* nc_n = (const int*)d_in[3];
    const int* nc_c = nc_n + N;
    const float* Wne0 = (const float*)d_in[7];
    const float* Wen0 = (const float*)d_in[8];
    const float* Wne1 = (const float*)d_in[11];
    const float* Wen1 = (const float*)d_in[12];
    const float* Wec1 = (const float*)d_in[13];
    const float* Wnc1 = (const float*)d_in[14];
    const float* alpha = (const float*)d_in[15];

    float* out_x = (float*)d_out;                 // [N,128]
    float* out_e = out_x + (size_t)N * 128;       // [E,128]
    float* out_c = out_e + (size_t)E * 128;       // [C,128]

    // ---- carve workspace ----
    char* w = (char*)d_ws;
    auto alloc = [&](size_t bytes) { char* p = w; w += (bytes + 255) & ~(size_t)255; return p; };
    int* counters = (int*)alloc((size_t)(E + N + 2 * C) * 4);
    int* deg_e  = counters;
    int* deg_n  = counters + E;
    int* cnt_cn = counters + E + N;
    int* cnt_ce = counters + E + N + C;
    int* off_e  = (int*)alloc((size_t)(E + 1) * 4);
    int* off_n  = (int*)alloc((size_t)(N + 1) * 4);
    int* off_cn = (int*)alloc((size_t)(C + 1) * 4);
    int* off_ce = (int*)alloc((size_t)(C + 1) * 4);
    int* cur_e  = (int*)alloc((size_t)E * 4);
    int* cur_n  = (int*)alloc((size_t)N * 4);
    int* cur_cn = (int*)alloc((size_t)C * 4);
    int* cur_ce = (int*)alloc((size_t)C * 4);
    int* csr_e  = (int*)alloc((size_t)NNZ * 4);
    int* csr_n  = (int*)alloc((size_t)NNZ * 4);
    int* csr_cn = (int*)alloc((size_t)N * 4);
    int* csr_ce = (int*)alloc((size_t)E * 4);
    int* tilesum  = (int*)alloc(64 * 4);
    int* tilebase = (int*)alloc(64 * 4);
    int* bcur_e = (int*)alloc(KB2 * 4);
    int* bcur_n = (int*)alloc(KB2 * 4);
    u32* stg_e  = (u32*)alloc((size_t)NNZ * 4);
    u32* stg_n  = (u32*)alloc((size_t)NNZ * 4);
    u32* xbf    = (u32*)alloc((size_t)N * 64 * 4);
    u32* x1bf   = (u32*)alloc((size_t)N * 64 * 4);
    u32* ybf    = (u32*)alloc((size_t)E * 64 * 4);
    u32* eactbf = (u32*)alloc((size_t)E * 64 * 4);
    float* xa   = (float*)alloc((size_t)E * 128 * 4);
    float* ca_e = (float*)alloc((size_t)C * 128 * 4);
    float* ca_n = (float*)alloc((size_t)C * 128 * 4);

    const int th = 256;
    const int t0 = (E + TS - 1) / TS;
    const int t1 = (N + TS - 1) / TS;
    const int t2 = (C + TS - 1) / TS;
    const int t3 = (C + TS - 1) / TS;
    const int t01 = t0 + t1, t012 = t01 + t2, t0123 = t012 + t3;
    const int npairs = N * 64;

    // ---- CSR build + x conversion ----
    hipMemsetAsync(counters, 0, (size_t)(E + N + 2 * C) * 4, stream);
    k_hist_cvt<<<(npairs + th - 1) / th, th, 0, stream>>>(
        (const float2*)x0, xbf, npairs, ni, ei, nc_c, ec_c,
        deg_e, deg_n, cnt_cn, cnt_ce, NNZ, N, E);
    k_scan_p1<<<t0123, 256, 0, stream>>>(deg_e, E, deg_n, N, cnt_cn, C, cnt_ce, C,
                                         t0, t01, t012, tilesum);
    k_scan_p2<<<1, 64, 0, stream>>>(tilesum, tilebase, t0, t01, t012, t0123,
                                    off_e, E, off_n, N, off_cn, C, off_ce, C);
    k_scan_p3<<<t0123, 256, 0, stream>>>(deg_e, off_e, cur_e, E,
                                         deg_n, off_n, cur_n, N,
                                         cnt_cn, off_cn, cur_cn, C,
                                         cnt_ce, off_ce, cur_ce, C,
                                         t0, t01, t012, tilebase);
    bool binned = (E <= 16384) && (N <= 65536) && (E >= KB2) && (N >= KB2);
    if (binned) {
        k_binit<<<1, 2 * KB2, 0, stream>>>(off_e, off_n, bcur_e, bcur_n, E, N);
        {
            dim3 ga((NNZ + CH - 1) / CH, 2);
            k_part_a<<<ga, 256, 0, stream>>>(ni, ei, bcur_e, bcur_n, stg_e, stg_n, NNZ, N, E);
        }
        k_part_b<<<2 * KB2, 256, 0, stream>>>(stg_e, stg_n, off_e, off_n, csr_e, csr_n, E, N);
        k_scat_comp<<<(N + th - 1) / th, th, 0, stream>>>(nc_n, nc_c, ec_e, ec_c,
                                                          cur_cn, cur_ce, csr_cn, csr_ce, N, E);
    } else {
        k_scatter<<<(NNZ + th - 1) / th, th, 0, stream>>>(ni, ei, nc_n, nc_c, ec_e, ec_c,
                                                          cur_e, cur_n, cur_cn, cur_ce,
                                                          csr_e, csr_n, csr_cn, csr_ce, NNZ, N, E);
    }

    const int gmlp = (E + 31) / 32;
    // ---- layer 1 ----
    k_agg4<<<(E + 3) / 4, 256, 0, stream>>>(xbf, csr_e, off_e, xa, nullptr, E, N, 0, alpha);
    k_mlp<<<gmlp, 256, 0, stream>>>(xa, Wne0, Wen0, nullptr, nullptr, ybf, E, alpha);
    k_agg4<<<(N + 3) / 4, 256, 0, stream>>>(ybf, csr_n, off_n, nullptr, x1bf, N, E, 1, alpha);
    // ---- layer 2 ----
    k_agg4<<<(E + 3) / 4, 256, 0, stream>>>(x1bf, csr_e, off_e, xa, nullptr, E, N, 0, alpha);
    k_mlp<<<gmlp, 256, 0, stream>>>(xa, Wne1, Wen1, out_e, eactbf, ybf, E, alpha);
    // ---- components ----
    {
        dim3 gC2((C + 3) / 4, 2);
        k_agg_c2<<<gC2, 256, 0, stream>>>(eactbf, csr_ce, off_ce, ca_e, E,
                                          x1bf,   csr_cn, off_cn, ca_n, N, C);
    }
    {
        dim3 gC((C + 63) / 64, 2);
        k_gemm128<<<gC, 256, 0, stream>>>(ca_e, Wec1, ca_n, Wnc1, out_c, C, alpha);
    }
    // ---- node output ----
    k_agg4<<<(N + 3) / 4, 256, 0, stream>>>(ybf, csr_n, off_n, out_x, nullptr, N, E, 1, alpha);
}

// Round 9
// 330.847 us; speedup vs baseline: 1.4472x; 1.1212x over previous
//
#include <hip/hip_runtime.h>
#include <stdint.h>

typedef unsigned int u32;
#define TS 4096     // scan tile size (fallback path)
#define KB2 256     // partition buckets per side
#define CH 2048     // entries per phase-A / bhist block

// ---------- bf16 helpers ----------
__device__ __forceinline__ float bflo(u32 u) { return __uint_as_float(u << 16); }
__device__ __forceinline__ float bfhi(u32 u) { return __uint_as_float(u & 0xffff0000u); }
__device__ __forceinline__ u32 f2bf(float x) {
    u32 u = __float_as_uint(x);
    return (u + 0x7fffu + ((u >> 16) & 1u)) >> 16;   // RNE
}
__device__ __forceinline__ u32 pack2(float a, float b) { return f2bf(a) | (f2bf(b) << 16); }

__device__ __forceinline__ int bstart2(int b, int total) {
    return (int)(((unsigned long long)b * (u32)total + KB2 - 1) / KB2);
}

// block-wide exclusive scan, 256 threads, one value per thread
__device__ __forceinline__ int blk_exscan(int v, int& total) {
    __shared__ int ws[5];
    int t = threadIdx.x, lane = t & 63, w = t >> 6;
    int inc = v;
    for (int d = 1; d < 64; d <<= 1) { int u = __shfl_up(inc, d, 64); if (lane >= d) inc += u; }
    __syncthreads();                    // protect ws across repeated calls
    if (lane == 63) ws[w] = inc;
    __syncthreads();
    if (t == 0) { int acc = 0; for (int i = 0; i < 4; ++i) { int x = ws[i]; ws[i] = acc; acc += x; } ws[4] = acc; }
    __syncthreads();
    total = ws[4];
    return ws[w] + (inc - v);
}

// ---------- x -> bf16 conversion (pure streaming) ----------
__global__ void k_cvt(const float2* __restrict__ in, u32* __restrict__ out, int npairs) {
    int j = blockIdx.x * blockDim.x + threadIdx.x;
    if (j < npairs) { float2 v = in[j]; out[j] = pack2(v.x, v.y); }
}

// ---------- bucket histogram (LDS) + comp histogram ----------
__global__ __launch_bounds__(256) void k_bhist(
        const int* __restrict__ ni, const int* __restrict__ ei,
        const int* __restrict__ nc_c, const int* __restrict__ ec_c,
        int* __restrict__ bcntE, int* __restrict__ bcntN,
        int* __restrict__ cnt_cn, int* __restrict__ cnt_ce,
        int nnz, int n, int e) {
    __shared__ int hE[KB2], hN[KB2];
    int t = threadIdx.x;
    hE[t] = 0; hN[t] = 0;
    __syncthreads();
    int base = blockIdx.x * CH;
    int lim = base + CH; if (lim > nnz) lim = nnz;
    for (int i = base + t; i < lim; i += 256) {
        u32 v = (u32)ni[i], eg = (u32)ei[i];
        if (v >= (u32)n) v = 0;
        if (eg >= (u32)e) eg = 0;
        atomicAdd(&hE[(int)(((unsigned long long)eg * KB2) / (u32)e)], 1);
        atomicAdd(&hN[(int)(((unsigned long long)v  * KB2) / (u32)n)], 1);
    }
    __syncthreads();
    if (hE[t]) atomicAdd(&bcntE[t], hE[t]);
    if (hN[t]) atomicAdd(&bcntN[t], hN[t]);
    // comp histogram, grid-stride
    int gid = blockIdx.x * 256 + t, stride = gridDim.x * 256;
    for (int j = gid; j < n + e; j += stride) {
        if (j < n) atomicAdd(&cnt_cn[nc_c[j]], 1);
        else       atomicAdd(&cnt_ce[ec_c[j - n]], 1);
    }
}

// ---------- scan bucket counts -> bases/cursors; scan comp counts -> offsets ----------
__global__ __launch_bounds__(256) void k_bscan(
        const int* __restrict__ bcntE, const int* __restrict__ bcntN,
        int* __restrict__ basesE, int* __restrict__ basesN,
        int* __restrict__ bcur_e, int* __restrict__ bcur_n,
        const int* __restrict__ cnt_cn, const int* __restrict__ cnt_ce,
        int* __restrict__ off_cn, int* __restrict__ off_ce,
        int* __restrict__ cur_cn, int* __restrict__ cur_ce, int c) {
    int t = threadIdx.x, tot;
    int v = bcntE[t];
    int ex = blk_exscan(v, tot);
    basesE[t] = ex; bcur_e[t] = ex;
    if (t == 0) basesE[KB2] = tot;
    v = bcntN[t];
    ex = blk_exscan(v, tot);
    basesN[t] = ex; bcur_n[t] = ex;
    if (t == 0) basesN[KB2] = tot;
    // comp arrays (C <= 512)
    int i0 = 2 * t, i1 = 2 * t + 1;
    int v0 = (i0 < c) ? cnt_cn[i0] : 0;
    int v1 = (i1 < c) ? cnt_cn[i1] : 0;
    ex = blk_exscan(v0 + v1, tot);
    if (i0 < c) { off_cn[i0] = ex;      cur_cn[i0] = ex; }
    if (i1 < c) { off_cn[i1] = ex + v0; cur_cn[i1] = ex + v0; }
    if (t == 0) off_cn[c] = tot;
    v0 = (i0 < c) ? cnt_ce[i0] : 0;
    v1 = (i1 < c) ? cnt_ce[i1] : 0;
    ex = blk_exscan(v0 + v1, tot);
    if (i0 < c) { off_ce[i0] = ex;      cur_ce[i0] = ex; }
    if (i1 < c) { off_ce[i1] = ex + v0; cur_ce[i1] = ex + v0; }
    if (t == 0) off_ce[c] = tot;
}

// ---------- phase A: LDS radix partition into bucket-contiguous staging ----------
__global__ __launch_bounds__(256) void k_part_a(
        const int* __restrict__ ni, const int* __restrict__ ei,
        int* __restrict__ bcur_e, int* __restrict__ bcur_n,
        u32* __restrict__ stg_e, u32* __restrict__ stg_n,
        int nnz, int n, int e) {
    __shared__ u32 pk[CH];
    __shared__ unsigned short bb[CH];
    __shared__ int hist[KB2];
    __shared__ int gb[KB2];
    int side = blockIdx.y;                 // 0: edge-keyed, 1: node-keyed
    int base = blockIdx.x * CH;
    int cnt  = nnz - base; if (cnt > CH) cnt = CH;
    int t = threadIdx.x;
    for (int i = t; i < KB2; i += 256) hist[i] = 0;
    __syncthreads();
    u32 total = side ? (u32)n : (u32)e;
    for (int i = t; i < cnt; i += 256) {
        int v = ni[base + i], eg = ei[base + i];
        u32 key = side ? (u32)v : (u32)eg;
        u32 pay = side ? (u32)eg : (u32)v;
        if (key >= total) key = 0;
        u32 b = (u32)(((unsigned long long)key * KB2) / total);
        pk[i] = side ? (pay | (key << 14)) : (pay | (key << 16));
        bb[i] = (unsigned short)b;
        atomicAdd(&hist[b], 1);
    }
    __syncthreads();
    int* cursor = side ? bcur_n : bcur_e;
    u32* stg    = side ? stg_n  : stg_e;
    if (t < KB2) {
        int h = hist[t];
        gb[t] = h ? atomicAdd(&cursor[t], h) : 0;
        hist[t] = 0;
    }
    __syncthreads();
    for (int i = t; i < cnt; i += 256) {
        int b = bb[i];
        int r = atomicAdd(&hist[b], 1);
        stg[gb[b] + r] = pk[i];
    }
}

// ---------- phase B: per-bucket degree count + offsets + CSR scatter ----------
__global__ __launch_bounds__(256) void k_part_b2(
        const u32* __restrict__ stg_e, const u32* __restrict__ stg_n,
        const int* __restrict__ basesE, const int* __restrict__ basesN,
        int* __restrict__ off_e, int* __restrict__ off_n,
        int* __restrict__ csr_e, int* __restrict__ csr_n, int e, int n) {
    __shared__ int lcnt[256];
    int b = blockIdx.x, t = threadIdx.x;
    const u32* stg; const int* bases; int* off; int* csr; int total; int shift; u32 mask;
    if (b < KB2) { stg = stg_e; bases = basesE; off = off_e; csr = csr_e; total = e; shift = 16; mask = 0xFFFFu; }
    else { b -= KB2; stg = stg_n; bases = basesN; off = off_n; csr = csr_n; total = n; shift = 14; mask = 0x3FFFu; }
    int lo = bstart2(b, total), hi = bstart2(b + 1, total);
    int nid = hi - lo;
    int sbase = bases[b], send = bases[b + 1];
    lcnt[t] = 0;
    __syncthreads();
    for (int i = sbase + t; i < send; i += 256) {
        int key = (int)(stg[i] >> shift);
        atomicAdd(&lcnt[key - lo], 1);
    }
    __syncthreads();
    int cval = (t < nid) ? lcnt[t] : 0;
    int tot;
    int ex = blk_exscan(cval, tot);      // internal syncs protect lcnt reuse
    int cursor = sbase + ex;
    if (t < nid) { off[lo + t] = cursor; lcnt[t] = cursor; }
    if (t == 0 && hi == total) off[total] = send;
    __syncthreads();
    for (int i = sbase + t; i < send; i += 256) {
        u32 s = stg[i];
        int key = (int)(s >> shift);
        int pay = (int)(s & mask);
        int p = atomicAdd(&lcnt[key - lo], 1);
        csr[p] = pay;
    }
}

// ---------- component scatter ----------
__global__ void k_scat_comp(const int* __restrict__ nc_n, const int* __restrict__ nc_c,
                            const int* __restrict__ ec_e, const int* __restrict__ ec_c,
                            int* __restrict__ cur_cn, int* __restrict__ cur_ce,
                            int* __restrict__ csr_cn, int* __restrict__ csr_ce, int n, int e) {
    int j = blockIdx.x * blockDim.x + threadIdx.x;
    if (j < n) { int c = nc_c[j]; csr_cn[atomicAdd(&cur_cn[c], 1)] = nc_n[j]; }
    if (j < e) { int c = ec_c[j]; csr_ce[atomicAdd(&cur_ce[c], 1)] = ec_e[j]; }
}

// ================= fallback path (generality guard; unused at these sizes) ========
__global__ void k_hist_fb(const int* __restrict__ ni, const int* __restrict__ ei,
                          const int* __restrict__ nc_c, const int* __restrict__ ec_c,
                          int* __restrict__ deg_e, int* __restrict__ deg_n,
                          int* __restrict__ cnt_cn, int* __restrict__ cnt_ce,
                          int nnz, int n, int e) {
    int j = blockIdx.x * blockDim.x + threadIdx.x;
    if (j < nnz) {
        atomicAdd(&deg_e[ei[j]], 1);
        atomicAdd(&deg_n[ni[j]], 1);
    }
    if (j < n) atomicAdd(&cnt_cn[nc_c[j]], 1);
    if (j < e) atomicAdd(&cnt_ce[ec_c[j]], 1);
}

__device__ __forceinline__ void scan_sel(int b, int t0, int t01, int t012,
        const int* c0, int* o0, int* u0, int n0,
        const int* c1, int* o1, int* u1, int n1,
        const int* c2, int* o2, int* u2, int n2,
        const int* c3, int* o3, int* u3, int n3,
        const int*& cnt, int*& off, int*& cur, int& n, int& tile) {
    if (b < t0)        { cnt = c0; off = o0; cur = u0; n = n0; tile = b; }
    else if (b < t01)  { cnt = c1; off = o1; cur = u1; n = n1; tile = b - t0; }
    else if (b < t012) { cnt = c2; off = o2; cur = u2; n = n2; tile = b - t01; }
    else               { cnt = c3; off = o3; cur = u3; n = n3; tile = b - t012; }
}

__global__ void k_scan_p1(const int* c0, int n0, const int* c1, int n1,
                          const int* c2, int n2, const int* c3, int n3,
                          int t0, int t01, int t012, int* __restrict__ tilesum) {
    __shared__ int ws[4];
    int b = blockIdx.x;
    const int* cnt; int* off; int* cur; int n; int tile;
    scan_sel(b, t0, t01, t012, c0, nullptr, nullptr, n0, c1, nullptr, nullptr, n1,
             c2, nullptr, nullptr, n2, c3, nullptr, nullptr, n3, cnt, off, cur, n, tile);
    int base = tile * TS + threadIdx.x * 16;
    int s = 0;
#pragma unroll
    for (int i = 0; i < 16; ++i) { int idx = base + i; if (idx < n) s += cnt[idx]; }
    for (int d = 32; d; d >>= 1) s += __shfl_xor(s, d, 64);
    int lane = threadIdx.x & 63, w = threadIdx.x >> 6;
    if (lane == 0) ws[w] = s;
    __syncthreads();
    if (threadIdx.x == 0) tilesum[b] = ws[0] + ws[1] + ws[2] + ws[3];
}

__global__ void k_scan_p2(const int* __restrict__ tilesum, int* __restrict__ tilebase,
                          int t0, int t01, int t012, int t0123,
                          int* o0, int n0, int* o1, int n1, int* o2, int n2, int* o3, int n3) {
    if (threadIdx.x != 0 || blockIdx.x != 0) return;
    int carry = 0;
    for (int b = 0;    b < t0;    ++b) { tilebase[b] = carry; carry += tilesum[b]; } o0[n0] = carry;
    carry = 0;
    for (int b = t0;   b < t01;   ++b) { tilebase[b] = carry; carry += tilesum[b]; } o1[n1] = carry;
    carry = 0;
    for (int b = t01;  b < t012;  ++b) { tilebase[b] = carry; carry += tilesum[b]; } o2[n2] = carry;
    carry = 0;
    for (int b = t012; b < t0123; ++b) { tilebase[b] = carry; carry += tilesum[b]; } o3[n3] = carry;
}

__global__ void k_scan_p3(const int* c0, int* o0, int* u0, int n0,
                          const int* c1, int* o1, int* u1, int n1,
                          const int* c2, int* o2, int* u2, int n2,
                          const int* c3, int* o3, int* u3, int n3,
                          int t0, int t01, int t012, const int* __restrict__ tilebase) {
    __shared__ int wsum[4];
    int b = blockIdx.x;
    const int* cnt; int* off; int* cur; int n; int tile;
    scan_sel(b, t0, t01, t012, c0, o0, u0, n0, c1, o1, u1, n1,
             c2, o2, u2, n2, c3, o3, u3, n3, cnt, off, cur, n, tile);
    int lane = threadIdx.x & 63, w = threadIdx.x >> 6;
    int base = tile * TS + threadIdx.x * 16;
    int vals[16];
    int s = 0;
#pragma unroll
    for (int i = 0; i < 16; ++i) { int idx = base + i; int v = (idx < n) ? cnt[idx] : 0; vals[i] = v; s += v; }
    int inc = s;
    for (int d = 1; d < 64; d <<= 1) { int u = __shfl_up(inc, d, 64); if (lane >= d) inc += u; }
    if (lane == 63) wsum[w] = inc;
    __syncthreads();
    if (threadIdx.x == 0) {
        int acc = tilebase[b];
        for (int i = 0; i < 4; ++i) { int t = wsum[i]; wsum[i] = acc; acc += t; }
    }
    __syncthreads();
    int ex = wsum[w] + (inc - s);
#pragma unroll
    for (int i = 0; i < 16; ++i) {
        int idx = base + i;
        if (idx < n) { off[idx] = ex; cur[idx] = ex; }
        ex += vals[i];
    }
}

__global__ void k_scatter(const int* __restrict__ ni, const int* __restrict__ ei,
                          const int* __restrict__ nc_n, const int* __restrict__ nc_c,
                          const int* __restrict__ ec_e, const int* __restrict__ ec_c,
                          int* __restrict__ cur_e, int* __restrict__ cur_n,
                          int* __restrict__ cur_cn, int* __restrict__ cur_ce,
                          int* __restrict__ csr_e, int* __restrict__ csr_n,
                          int* __restrict__ csr_cn, int* __restrict__ csr_ce,
                          int nnz, int n, int e) {
    int j = blockIdx.x * blockDim.x + threadIdx.x;
    if (j < nnz) {
        int v = ni[j], eg = ei[j];
        csr_e[atomicAdd(&cur_e[eg], 1)] = v;
        csr_n[atomicAdd(&cur_n[v], 1)] = eg;
    }
    if (j < n) { int c = nc_c[j]; csr_cn[atomicAdd(&cur_cn[c], 1)] = nc_n[j]; }
    if (j < e) { int c = ec_c[j]; csr_ce[atomicAdd(&cur_ce[c], 1)] = ec_e[j]; }
}
// ================= end fallback =================

// ---------- segment mean: wave per segment, 4 rows per load instruction ----------
__device__ __forceinline__ void agg4_body(const u32* __restrict__ in,
                                          const int* __restrict__ items,
                                          const int* __restrict__ off,
                                          float* __restrict__ out_f32,
                                          u32* __restrict__ out_bf,
                                          int nseg, int nrows, int do_prelu,
                                          const float* __restrict__ alpha_p, int seg) {
    int lane = threadIdx.x & 63;
    int rs = lane >> 4;
    int cc = lane & 15;
    if (seg >= nseg) return;
    int s0 = off[seg], s1 = off[seg + 1];
    const uint4* rows = (const uint4*)in;
    float a[8];
#pragma unroll
    for (int i = 0; i < 8; ++i) a[i] = 0.f;
    int base = s0;
    for (; base + 8 <= s1; base += 8) {
        u32 r0 = (u32)items[base + rs];
        u32 r1 = (u32)items[base + 4 + rs];
        r0 = (r0 < (u32)nrows) ? r0 : 0u;
        r1 = (r1 < (u32)nrows) ? r1 : 0u;
        uint4 v0 = rows[(size_t)r0 * 16 + cc];
        uint4 v1 = rows[(size_t)r1 * 16 + cc];
        a[0] += bflo(v0.x); a[1] += bfhi(v0.x); a[2] += bflo(v0.y); a[3] += bfhi(v0.y);
        a[4] += bflo(v0.z); a[5] += bfhi(v0.z); a[6] += bflo(v0.w); a[7] += bfhi(v0.w);
        a[0] += bflo(v1.x); a[1] += bfhi(v1.x); a[2] += bflo(v1.y); a[3] += bfhi(v1.y);
        a[4] += bflo(v1.z); a[5] += bfhi(v1.z); a[6] += bflo(v1.w); a[7] += bfhi(v1.w);
    }
    int idx = base + rs;
    if (idx < s1) {
        u32 r = (u32)items[idx]; r = (r < (u32)nrows) ? r : 0u;
        uint4 v = rows[(size_t)r * 16 + cc];
        a[0] += bflo(v.x); a[1] += bfhi(v.x); a[2] += bflo(v.y); a[3] += bfhi(v.y);
        a[4] += bflo(v.z); a[5] += bfhi(v.z); a[6] += bflo(v.w); a[7] += bfhi(v.w);
    }
    idx += 4;
    if (idx < s1) {
        u32 r = (u32)items[idx]; r = (r < (u32)nrows) ? r : 0u;
        uint4 v = rows[(size_t)r * 16 + cc];
        a[0] += bflo(v.x); a[1] += bfhi(v.x); a[2] += bflo(v.y); a[3] += bfhi(v.y);
        a[4] += bflo(v.z); a[5] += bfhi(v.z); a[6] += bflo(v.w); a[7] += bfhi(v.w);
    }
#pragma unroll
    for (int i = 0; i < 8; ++i) {
        a[i] += __shfl_xor(a[i], 16, 64);
        a[i] += __shfl_xor(a[i], 32, 64);
    }
    float inv = 1.f / fmaxf((float)(s1 - s0), 1.f);
#pragma unroll
    for (int i = 0; i < 8; ++i) a[i] *= inv;
    if (do_prelu) {
        float al = *alpha_p;
#pragma unroll
        for (int i = 0; i < 8; ++i) a[i] = (a[i] >= 0.f) ? a[i] : al * a[i];
    }
    if (rs == 0) {
        if (out_f32) {
            float* o = out_f32 + ((size_t)seg << 7) + cc * 8;
            *(float4*)o       = make_float4(a[0], a[1], a[2], a[3]);
            *(float4*)(o + 4) = make_float4(a[4], a[5], a[6], a[7]);
        }
        if (out_bf) {
            uint4 pk;
            pk.x = pack2(a[0], a[1]); pk.y = pack2(a[2], a[3]);
            pk.z = pack2(a[4], a[5]); pk.w = pack2(a[6], a[7]);
            *(uint4*)(out_bf + ((size_t)seg << 6) + cc * 4) = pk;
        }
    }
}

__global__ void k_agg4(const u32* __restrict__ in, const int* __restrict__ items,
                       const int* __restrict__ off, float* __restrict__ out_f32,
                       u32* __restrict__ out_bf,
                       int nseg, int nrows, int do_prelu, const float* __restrict__ alpha_p) {
    int seg = blockIdx.x * (blockDim.x >> 6) + (threadIdx.x >> 6);
    agg4_body(in, items, off, out_f32, out_bf, nseg, nrows, do_prelu, alpha_p, seg);
}

__global__ void k_agg_c2(const u32* inA, const int* itemsA, const int* offA, float* outA, int nrowsA,
                         const u32* inB, const int* itemsB, const int* offB, float* outB, int nrowsB,
                         int nseg) {
    int seg = blockIdx.x * (blockDim.x >> 6) + (threadIdx.x >> 6);
    if (blockIdx.y == 0) agg4_body(inA, itemsA, offA, outA, nullptr, nseg, nrowsA, 0, nullptr, seg);
    else                 agg4_body(inB, itemsB, offB, outB, nullptr, nseg, nrowsB, 0, nullptr, seg);
}

// ---------- fused 2-layer MLP ----------
__global__ __launch_bounds__(256) void k_mlp(
        const float* __restrict__ A, const float* __restrict__ W1,
        const float* __restrict__ W2,
        float* __restrict__ out_raw, u32* __restrict__ out_actbf,
        u32* __restrict__ out_ybf,
        int M, const float* __restrict__ alpha_p) {
    __shared__ float As[32 * 132];
    __shared__ float Ws[128 * 64];
    int t  = threadIdx.x;
    int rb = blockIdx.x * 32;
    int cg = t & 7, rg = t >> 3;
    int row = rb + rg;

    for (int i = t; i < 32 * 32; i += 256) {
        int r = i >> 5, dc = i & 31;
        int arow = rb + r;
        float4 v = make_float4(0.f, 0.f, 0.f, 0.f);
        if (arow < M) v = *(const float4*)(A + ((size_t)arow << 7) + dc * 4);
        *(float4*)&As[r * 132 + dc * 4] = v;
    }

    float e[2][8];
#pragma unroll
    for (int h = 0; h < 2; ++h) {
        __syncthreads();
        for (int i = t; i < 128 * 16; i += 256) {
            int k = i >> 4, dc = i & 15;
            *(float4*)&Ws[k * 64 + dc * 4] = *(const float4*)(W1 + ((size_t)k << 7) + h * 64 + dc * 4);
        }
        __syncthreads();
        float acc[8];
#pragma unroll
        for (int i = 0; i < 8; ++i) acc[i] = 0.f;
        for (int k = 0; k < 128; ++k) {
            float av = As[rg * 132 + k];
            float4 w0 = *(const float4*)&Ws[k * 64 + cg * 8];
            float4 w1 = *(const float4*)&Ws[k * 64 + cg * 8 + 4];
            acc[0] += av * w0.x; acc[1] += av * w0.y; acc[2] += av * w0.z; acc[3] += av * w0.w;
            acc[4] += av * w1.x; acc[5] += av * w1.y; acc[6] += av * w1.z; acc[7] += av * w1.w;
        }
#pragma unroll
        for (int i = 0; i < 8; ++i) e[h][i] = acc[i];
    }
    __syncthreads();

    float al = *alpha_p;
    if (row < M && out_raw) {
#pragma unroll
        for (int h = 0; h < 2; ++h) {
            float* o = out_raw + ((size_t)row << 7) + h * 64 + cg * 8;
            *(float4*)o       = make_float4(e[h][0], e[h][1], e[h][2], e[h][3]);
            *(float4*)(o + 4) = make_float4(e[h][4], e[h][5], e[h][6], e[h][7]);
        }
    }
    float act[2][8];
#pragma unroll
    for (int h = 0; h < 2; ++h)
#pragma unroll
        for (int i = 0; i < 8; ++i) { float x = e[h][i]; act[h][i] = (x >= 0.f) ? x : al * x; }
    if (row < M && out_actbf) {
#pragma unroll
        for (int h = 0; h < 2; ++h) {
            uint4 pk;
            pk.x = pack2(act[h][0], act[h][1]); pk.y = pack2(act[h][2], act[h][3]);
            pk.z = pack2(act[h][4], act[h][5]); pk.w = pack2(act[h][6], act[h][7]);
            *(uint4*)(out_actbf + ((size_t)row << 6) + h * 32 + cg * 4) = pk;
        }
    }
#pragma unroll
    for (int h = 0; h < 2; ++h) {
        *(float4*)&As[rg * 132 + h * 64 + cg * 8]     = make_float4(act[h][0], act[h][1], act[h][2], act[h][3]);
        *(float4*)&As[rg * 132 + h * 64 + cg * 8 + 4] = make_float4(act[h][4], act[h][5], act[h][6], act[h][7]);
    }

    float y[2][8];
#pragma unroll
    for (int h = 0; h < 2; ++h) {
        __syncthreads();
        for (int i = t; i < 128 * 16; i += 256) {
            int k = i >> 4, dc = i & 15;
            *(float4*)&Ws[k * 64 + dc * 4] = *(const float4*)(W2 + ((size_t)k << 7) + h * 64 + dc * 4);
        }
        __syncthreads();
        float acc[8];
#pragma unroll
        for (int i = 0; i < 8; ++i) acc[i] = 0.f;
        for (int k = 0; k < 128; ++k) {
            float av = As[rg * 132 + k];
            float4 w0 = *(const float4*)&Ws[k * 64 + cg * 8];
            float4 w1 = *(const float4*)&Ws[k * 64 + cg * 8 + 4];
            acc[0] += av * w0.x; acc[1] += av * w0.y; acc[2] += av * w0.z; acc[3] += av * w0.w;
            acc[4] += av * w1.x; acc[5] += av * w1.y; acc[6] += av * w1.z; acc[7] += av * w1.w;
        }
#pragma unroll
        for (int i = 0; i < 8; ++i) y[h][i] = acc[i];
    }
    if (row < M && out_ybf) {
#pragma unroll
        for (int h = 0; h < 2; ++h) {
            uint4 pk;
            pk.x = pack2(y[h][0], y[h][1]); pk.y = pack2(y[h][2], y[h][3]);
            pk.z = pack2(y[h][4], y[h][5]); pk.w = pack2(y[h][6], y[h][7]);
            *(uint4*)(out_ybf + ((size_t)row << 6) + h * 32 + cg * 4) = pk;
        }
    }
}

// ---------- component GEMM: pair-accumulate [C,128]@[128,128] ----------
__global__ __launch_bounds__(256) void k_gemm128(
        const float* __restrict__ A,  const float* __restrict__ W,
        const float* __restrict__ A2, const float* __restrict__ W2,
        float* __restrict__ out_raw,
        int M, const float* __restrict__ alpha_p) {
    __shared__ float As[64 * 128];
    __shared__ float Ws[128 * 64];
    int t  = threadIdx.x;
    int rb = blockIdx.x * 64;
    int cb = blockIdx.y * 64;
    int cg = t & 7, rg = t >> 3;
    int c0 = cg * 8;
    int sw = (rg & 7) << 2;

    float acc[16];
#pragma unroll
    for (int i = 0; i < 16; ++i) acc[i] = 0.f;

    for (int pair = 0; pair < 2; ++pair) {
        const float* Ap = pair ? A2 : A;
        const float* Wp = pair ? W2 : W;
        if (pair) __syncthreads();
        for (int i = t; i < 64 * 32; i += 256) {
            int r = i >> 5, dc = i & 31;
            int row = rb + r;
            float4 v = make_float4(0.f, 0.f, 0.f, 0.f);
            if (row < M) v = *(const float4*)(Ap + ((size_t)row << 7) + dc * 4);
            int swr = (r & 7) << 2;
            *(float4*)&As[r * 128 + ((dc * 4) ^ swr)] = v;
        }
        for (int i = t; i < 128 * 16; i += 256) {
            int k = i >> 4, dc = i & 15;
            *(float4*)&Ws[k * 64 + dc * 4] = *(const float4*)(Wp + ((size_t)k << 7) + cb + dc * 4);
        }
        __syncthreads();
#pragma unroll 4
        for (int k = 0; k < 128; ++k) {
            float a0 = As[rg * 128 + (k ^ sw)];
            float a1 = As[(rg + 32) * 128 + (k ^ sw)];
            const float* wr = &Ws[k * 64 + c0];
            float4 w0 = *(const float4*)(wr);
            float4 w1 = *(const float4*)(wr + 4);
            acc[0]  += a0 * w0.x; acc[1]  += a0 * w0.y; acc[2]  += a0 * w0.z; acc[3]  += a0 * w0.w;
            acc[4]  += a0 * w1.x; acc[5]  += a0 * w1.y; acc[6]  += a0 * w1.z; acc[7]  += a0 * w1.w;
            acc[8]  += a1 * w0.x; acc[9]  += a1 * w0.y; acc[10] += a1 * w0.z; acc[11] += a1 * w0.w;
            acc[12] += a1 * w1.x; acc[13] += a1 * w1.y; acc[14] += a1 * w1.z; acc[15] += a1 * w1.w;
        }
    }
#pragma unroll
    for (int h = 0; h < 2; ++h) {
        int row = rb + rg + h * 32;
        if (row >= M) continue;
        size_t ob = ((size_t)row << 7) + cb + c0;
        *(float4*)(out_raw + ob)     = make_float4(acc[h*8+0], acc[h*8+1], acc[h*8+2], acc[h*8+3]);
        *(float4*)(out_raw + ob + 4) = make_float4(acc[h*8+4], acc[h*8+5], acc[h*8+6], acc[h*8+7]);
    }
}

extern "C" void kernel_launch(void* const* d_in, const int* in_sizes, int n_in,
                              void* d_out, int out_size, void* d_ws, size_t ws_size,
                              hipStream_t stream) {
    const int N   = in_sizes[0] / 128;   // 50000
    const int NNZ = in_sizes[1] / 2;     // 400000
    const int E   = in_sizes[2] / 2;     // 10000
    const int C   = 500;

    const float* x0 = (const float*)d_in[0];
    const int* ni   = (const int*)d_in[1];
    const int* ei   = ni + NNZ;
    const int* ec_e = (const int*)d_in[2];
    const int* ec_c = ec_e + E;
    const int* nc_n = (const int*)d_in[3];
    const int* nc_c = nc_n + N;
    const float* Wne0 = (const float*)d_in[7];
    const float* Wen0 = (const float*)d_in[8];
    const float* Wne1 = (const float*)d_in[11];
    const float* Wen1 = (const float*)d_in[12];
    const float* Wec1 = (const float*)d_in[13];
    const float* Wnc1 = (const float*)d_in[14];
    const float* alpha = (const float*)d_in[15];

    float* out_x = (float*)d_out;                 // [N,128]
    float* out_e = out_x + (size_t)N * 128;       // [E,128]
    float* out_c = out_e + (size_t)E * 128;       // [C,128]

    // ---- carve workspace ----
    char* w = (char*)d_ws;
    auto alloc = [&](size_t bytes) { char* p = w; w += (bytes + 255) & ~(size_t)255; return p; };
    // zero-init group: bcntE | bcntN | cnt_cn | cnt_ce
    int* zgrp   = (int*)alloc((size_t)(2 * KB2 + 2 * C) * 4);
    int* bcntE  = zgrp;
    int* bcntN  = zgrp + KB2;
    int* cnt_cn = zgrp + 2 * KB2;
    int* cnt_ce = zgrp + 2 * KB2 + C;
    int* off_e  = (int*)alloc((size_t)(E + 1) * 4);
    int* off_n  = (int*)alloc((size_t)(N + 1) * 4);
    int* off_cn = (int*)alloc((size_t)(C + 1) * 4);
    int* off_ce = (int*)alloc((size_t)(C + 1) * 4);
    int* cur_cn = (int*)alloc((size_t)C * 4);
    int* cur_ce = (int*)alloc((size_t)C * 4);
    int* csr_e  = (int*)alloc((size_t)NNZ * 4);
    int* csr_n  = (int*)alloc((size_t)NNZ * 4);
    int* csr_cn = (int*)alloc((size_t)N * 4);
    int* csr_ce = (int*)alloc((size_t)E * 4);
    int* basesE = (int*)alloc((size_t)(KB2 + 1) * 4);
    int* basesN = (int*)alloc((size_t)(KB2 + 1) * 4);
    int* bcur_e = (int*)alloc(KB2 * 4);
    int* bcur_n = (int*)alloc(KB2 * 4);
    u32* stg_e  = (u32*)alloc((size_t)NNZ * 4);
    u32* stg_n  = (u32*)alloc((size_t)NNZ * 4);
    u32* xbf    = (u32*)alloc((size_t)N * 64 * 4);
    u32* x1bf   = (u32*)alloc((size_t)N * 64 * 4);
    u32* ybf    = (u32*)alloc((size_t)E * 64 * 4);
    u32* eactbf = (u32*)alloc((size_t)E * 64 * 4);
    float* xa   = (float*)alloc((size_t)E * 128 * 4);
    float* ca_e = (float*)alloc((size_t)C * 128 * 4);
    float* ca_n = (float*)alloc((size_t)C * 128 * 4);
    // fallback-only buffers
    int* deg_e    = (int*)alloc((size_t)E * 4);
    int* deg_n    = (int*)alloc((size_t)N * 4);
    int* cur_e    = (int*)alloc((size_t)E * 4);
    int* cur_n    = (int*)alloc((size_t)N * 4);
    int* tilesum  = (int*)alloc(64 * 4);
    int* tilebase = (int*)alloc(64 * 4);

    const int th = 256;
    const int npairs = N * 64;
    const int nbh = (NNZ + CH - 1) / CH;

    k_cvt<<<(npairs + th - 1) / th, th, 0, stream>>>((const float2*)x0, xbf, npairs);

    bool binned = (E <= 16384) && (N <= 65536) && (E >= KB2) && (N >= KB2) &&
                  ((N + KB2 - 1) / KB2 <= 256) && (C <= 512);
    if (binned) {
        hipMemsetAsync(zgrp, 0, (size_t)(2 * KB2 + 2 * C) * 4, stream);
        k_bhist<<<nbh, 256, 0, stream>>>(ni, ei, nc_c, ec_c, bcntE, bcntN, cnt_cn, cnt_ce, NNZ, N, E);
        k_bscan<<<1, 256, 0, stream>>>(bcntE, bcntN, basesE, basesN, bcur_e, bcur_n,
                                       cnt_cn, cnt_ce, off_cn, off_ce, cur_cn, cur_ce, C);
        {
            dim3 ga(nbh, 2);
            k_part_a<<<ga, 256, 0, stream>>>(ni, ei, bcur_e, bcur_n, stg_e, stg_n, NNZ, N, E);
        }
        k_part_b2<<<2 * KB2, 256, 0, stream>>>(stg_e, stg_n, basesE, basesN,
                                               off_e, off_n, csr_e, csr_n, E, N);
        k_scat_comp<<<(N + th - 1) / th, th, 0, stream>>>(nc_n, nc_c, ec_e, ec_c,
                                                          cur_cn, cur_ce, csr_cn, csr_ce, N, E);
    } else {
        hipMemsetAsync(zgrp, 0, (size_t)(2 * KB2 + 2 * C) * 4, stream);
        hipMemsetAsync(deg_e, 0, (size_t)E * 4, stream);
        hipMemsetAsync(deg_n, 0, (size_t)N * 4, stream);
        k_hist_fb<<<(NNZ > N + E ? NNZ : N + E) / th + 1, th, 0, stream>>>(
            ni, ei, nc_c, ec_c, deg_e, deg_n, cnt_cn, cnt_ce, NNZ, N, E);
        const int t0 = (E + TS - 1) / TS, t1 = (N + TS - 1) / TS;
        const int t2 = (C + TS - 1) / TS, t3 = (C + TS - 1) / TS;
        const int t01 = t0 + t1, t012 = t01 + t2, t0123 = t012 + t3;
        k_scan_p1<<<t0123, 256, 0, stream>>>(deg_e, E, deg_n, N, cnt_cn, C, cnt_ce, C,
                                             t0, t01, t012, tilesum);
        k_scan_p2<<<1, 64, 0, stream>>>(tilesum, tilebase, t0, t01, t012, t0123,
                                        off_e, E, off_n, N, off_cn, C, off_ce, C);
        k_scan_p3<<<t0123, 256, 0, stream>>>(deg_e, off_e, cur_e, E,
                                             deg_n, off_n, cur_n, N,
                                             cnt_cn, off_cn, cur_cn, C,
                                             cnt_ce, off_ce, cur_ce, C,
                                             t0, t01, t012, tilebase);
        k_scatter<<<(NNZ + th - 1) / th, th, 0, stream>>>(ni, ei, nc_n, nc_c, ec_e, ec_c,
                                                          cur_e, cur_n, cur_cn, cur_ce,
                                                          csr_e, csr_n, csr_cn, csr_ce, NNZ, N, E);
    }

    const int gmlp = (E + 31) / 32;
    // ---- layer 1 ----
    k_agg4<<<(E + 3) / 4, 256, 0, stream>>>(xbf, csr_e, off_e, xa, nullptr, E, N, 0, alpha);
    k_mlp<<<gmlp, 256, 0, stream>>>(xa, Wne0, Wen0, nullptr, nullptr, ybf, E, alpha);
    k_agg4<<<(N + 3) / 4, 256, 0, stream>>>(ybf, csr_n, off_n, nullptr, x1bf, N, E, 1, alpha);
    // ---- layer 2 ----
    k_agg4<<<(E + 3) / 4, 256, 0, stream>>>(x1bf, csr_e, off_e, xa, nullptr, E, N, 0, alpha);
    k_mlp<<<gmlp, 256, 0, stream>>>(xa, Wne1, Wen1, out_e, eactbf, ybf, E, alpha);
    // ---- components ----
    {
        dim3 gC2((C + 3) / 4, 2);
        k_agg_c2<<<gC2, 256, 0, stream>>>(eactbf, csr_ce, off_ce, ca_e, E,
                                          x1bf,   csr_cn, off_cn, ca_n, N, C);
    }
    {
        dim3 gC((C + 63) / 64, 2);
        k_gemm128<<<gC, 256, 0, stream>>>(ca_e, Wec1, ca_n, Wnc1, out_c, C, alpha);
    }
    // ---- node output ----
    k_agg4<<<(N + 3) / 4, 256, 0, stream>>>(ybf, csr_n, off_n, out_x, nullptr, N, E, 1, alpha);
}